// Round 1
// baseline (1524.256 us; speedup 1.0000x reference)
//
#include <hip/hip_runtime.h>
#include <math.h>

#define D 128
#define EB 64
#define NB 64

typedef unsigned int u32;
typedef unsigned short u16;

__device__ __forceinline__ float bfl(u32 u) { return __uint_as_float(u << 16); }
__device__ __forceinline__ float bfh(u32 u) { return __uint_as_float(u & 0xFFFF0000u); }
__device__ __forceinline__ u16 f2bf(float f) {
    u32 u = __float_as_uint(f);
    return (u16)((u + 0x7FFFu + ((u >> 16) & 1u)) >> 16); // RNE
}
__device__ __forceinline__ float silu_f(float x) { return x / (1.0f + __expf(-x)); }

// ---------------- coord: out = remainder(coord, l) ----------------
__global__ void coord_kernel(const float* __restrict__ coord,
                             const float* __restrict__ lbox,
                             float* __restrict__ out, int n3) {
    int i = blockIdx.x * 256 + threadIdx.x;
    if (i < n3) {
        float ld = lbox[i % 3];
        float c = coord[i];
        float r = fmodf(c, ld);
        if (r < 0.f) r += ld;
        out[i] = r;
    }
}

// ---------------- edge model + scatter-add ----------------
__global__ __launch_bounds__(256) void edge_kernel(
    const float* __restrict__ h, const int* __restrict__ ei,
    const float* __restrict__ coord, const float* __restrict__ lbox,
    const float* __restrict__ We1, const float* __restrict__ be1,
    const float* __restrict__ We2, const float* __restrict__ be2,
    float* __restrict__ ef_out, float* __restrict__ agg, int E)
{
    __shared__ u16 sX[257][EB];   // transposed concat inputs, bf16
    __shared__ u16 sE[128][72];   // layer-1 activations, stride 72 (16B aligned, fewer write conflicts)
    __shared__ int srow[EB], scol[EB];

    const int t = threadIdx.x;
    const int lane = t & 63;
    const int q = t >> 6;
    const int e0 = blockIdx.x * EB;

    if (t < EB) {
        int eg = e0 + t;
        srow[t] = (eg < E) ? ei[eg] : 0;
        scol[t] = (eg < E) ? ei[(size_t)E + eg] : 0;
    }
    __syncthreads();

    // stage: thread (lane=edge, q=k-chunk of 32)
    {
        const int r = srow[lane], c = scol[lane];
        const float4* hr = (const float4*)(h + (size_t)r * D) + q * 8;
        const float4* hc = (const float4*)(h + (size_t)c * D) + q * 8;
        #pragma unroll
        for (int i = 0; i < 8; ++i) {
            float4 v = hr[i];
            float4 w = hc[i];
            int k = q * 32 + i * 4;
            sX[k+0][lane] = f2bf(v.x); sX[k+1][lane] = f2bf(v.y);
            sX[k+2][lane] = f2bf(v.z); sX[k+3][lane] = f2bf(v.w);
            sX[128+k+0][lane] = f2bf(w.x); sX[128+k+1][lane] = f2bf(w.y);
            sX[128+k+2][lane] = f2bf(w.z); sX[128+k+3][lane] = f2bf(w.w);
        }
        if (q == 0) {
            float rad = 0.f;
            #pragma unroll
            for (int d3 = 0; d3 < 3; ++d3) {
                float df = coord[(size_t)r*3 + d3] - coord[(size_t)c*3 + d3];
                float ld = lbox[d3];
                df = (df >  0.5f*ld) ? df - ld : df;
                df = (df < -0.5f*ld) ? df + ld : df;
                rad += df * df;
            }
            sX[256][lane] = f2bf(rad);
        }
    }
    __syncthreads();

    const int jj = lane;
    // layer 1: K=257
    float acc0[16], acc1[16];
    {
        float b0 = be1[jj], b1 = be1[jj + 64];
        #pragma unroll
        for (int i = 0; i < 16; ++i) { acc0[i] = b0; acc1[i] = b1; }
    }
    #pragma unroll 2
    for (int k = 0; k < 257; ++k) {
        float w0 = We1[(size_t)k*D + jj];
        float w1 = We1[(size_t)k*D + jj + 64];
        const u32* xp = (const u32*)&sX[k][q*16];
        #pragma unroll
        for (int p = 0; p < 8; ++p) {
            u32 u = xp[p];
            float xa = bfl(u), xb = bfh(u);
            acc0[2*p]   += xa*w0; acc1[2*p]   += xa*w1;
            acc0[2*p+1] += xb*w0; acc1[2*p+1] += xb*w1;
        }
    }
    #pragma unroll
    for (int p = 0; p < 8; ++p) {
        u32 pk0 = (u32)f2bf(silu_f(acc0[2*p])) | ((u32)f2bf(silu_f(acc0[2*p+1])) << 16);
        u32 pk1 = (u32)f2bf(silu_f(acc1[2*p])) | ((u32)f2bf(silu_f(acc1[2*p+1])) << 16);
        *(u32*)&sE[jj][q*16 + 2*p] = pk0;
        *(u32*)&sE[jj+64][q*16 + 2*p] = pk1;
    }
    __syncthreads();

    // layer 2: K=128
    float o0[16], o1[16];
    {
        float b0 = be2[jj], b1 = be2[jj + 64];
        #pragma unroll
        for (int i = 0; i < 16; ++i) { o0[i] = b0; o1[i] = b1; }
    }
    #pragma unroll 2
    for (int k = 0; k < 128; ++k) {
        float w0 = We2[(size_t)k*D + jj];
        float w1 = We2[(size_t)k*D + jj + 64];
        const u32* xp = (const u32*)&sE[k][q*16];
        #pragma unroll
        for (int p = 0; p < 8; ++p) {
            u32 u = xp[p];
            float xa = bfl(u), xb = bfh(u);
            o0[2*p]   += xa*w0; o1[2*p]   += xa*w1;
            o0[2*p+1] += xb*w0; o1[2*p+1] += xb*w1;
        }
    }
    #pragma unroll
    for (int i = 0; i < 16; ++i) {
        int el = q*16 + i;
        int eg = e0 + el;
        if (eg < E) {
            float v0 = silu_f(o0[i]);
            float v1 = silu_f(o1[i]);
            ef_out[(size_t)eg*D + jj] = v0;
            ef_out[(size_t)eg*D + jj + 64] = v1;
            int rg = srow[el];
            atomicAdd(&agg[(size_t)rg*D + jj], v0);
            atomicAdd(&agg[(size_t)rg*D + jj + 64], v1);
        }
    }
}

// ---------------- node model (reads agg in-place, overwrites with h_out) ----------------
__global__ __launch_bounds__(256) void node_kernel(
    const float* __restrict__ h, const float* __restrict__ agg,
    const float* __restrict__ Wn1, const float* __restrict__ bn1,
    const float* __restrict__ Wn2, const float* __restrict__ bn2,
    float* __restrict__ h_out, int N)
{
    __shared__ u16 sX[256][NB];
    __shared__ u16 sE[128][72];

    const int t = threadIdx.x;
    const int lane = t & 63;
    const int q = t >> 6;
    const int n0 = blockIdx.x * NB;
    const int n = n0 + lane;
    const bool valid = n < N;

    {
        const float4* hr = (const float4*)(h + (size_t)n * D) + q * 8;
        const float4* ar = (const float4*)(agg + (size_t)n * D) + q * 8;
        #pragma unroll
        for (int i = 0; i < 8; ++i) {
            float4 v = valid ? hr[i] : make_float4(0.f,0.f,0.f,0.f);
            float4 w = valid ? ar[i] : make_float4(0.f,0.f,0.f,0.f);
            int k = q * 32 + i * 4;
            sX[k+0][lane] = f2bf(v.x); sX[k+1][lane] = f2bf(v.y);
            sX[k+2][lane] = f2bf(v.z); sX[k+3][lane] = f2bf(v.w);
            sX[128+k+0][lane] = f2bf(w.x); sX[128+k+1][lane] = f2bf(w.y);
            sX[128+k+2][lane] = f2bf(w.z); sX[128+k+3][lane] = f2bf(w.w);
        }
    }
    __syncthreads();

    const int jj = lane;
    float acc0[16], acc1[16];
    {
        float b0 = bn1[jj], b1 = bn1[jj + 64];
        #pragma unroll
        for (int i = 0; i < 16; ++i) { acc0[i] = b0; acc1[i] = b1; }
    }
    #pragma unroll 2
    for (int k = 0; k < 256; ++k) {
        float w0 = Wn1[(size_t)k*D + jj];
        float w1 = Wn1[(size_t)k*D + jj + 64];
        const u32* xp = (const u32*)&sX[k][q*16];
        #pragma unroll
        for (int p = 0; p < 8; ++p) {
            u32 u = xp[p];
            float xa = bfl(u), xb = bfh(u);
            acc0[2*p]   += xa*w0; acc1[2*p]   += xa*w1;
            acc0[2*p+1] += xb*w0; acc1[2*p+1] += xb*w1;
        }
    }
    #pragma unroll
    for (int p = 0; p < 8; ++p) {
        u32 pk0 = (u32)f2bf(silu_f(acc0[2*p])) | ((u32)f2bf(silu_f(acc0[2*p+1])) << 16);
        u32 pk1 = (u32)f2bf(silu_f(acc1[2*p])) | ((u32)f2bf(silu_f(acc1[2*p+1])) << 16);
        *(u32*)&sE[jj][q*16 + 2*p] = pk0;
        *(u32*)&sE[jj+64][q*16 + 2*p] = pk1;
    }
    __syncthreads();

    float o0[16], o1[16];
    {
        float b0 = bn2[jj], b1 = bn2[jj + 64];
        #pragma unroll
        for (int i = 0; i < 16; ++i) { o0[i] = b0; o1[i] = b1; }
    }
    #pragma unroll 2
    for (int k = 0; k < 128; ++k) {
        float w0 = Wn2[(size_t)k*D + jj];
        float w1 = Wn2[(size_t)k*D + jj + 64];
        const u32* xp = (const u32*)&sE[k][q*16];
        #pragma unroll
        for (int p = 0; p < 8; ++p) {
            u32 u = xp[p];
            float xa = bfl(u), xb = bfh(u);
            o0[2*p]   += xa*w0; o1[2*p]   += xa*w1;
            o0[2*p+1] += xb*w0; o1[2*p+1] += xb*w1;
        }
    }
    #pragma unroll
    for (int i = 0; i < 16; ++i) {
        int nl = q*16 + i;
        int ng = n0 + nl;
        if (ng < N) {
            h_out[(size_t)ng*D + jj]      = h[(size_t)ng*D + jj]      + o0[i];
            h_out[(size_t)ng*D + jj + 64] = h[(size_t)ng*D + jj + 64] + o1[i];
        }
    }
}

extern "C" void kernel_launch(void* const* d_in, const int* in_sizes, int n_in,
                              void* d_out, int out_size, void* d_ws, size_t ws_size,
                              hipStream_t stream) {
    const float* h     = (const float*)d_in[0];
    const int*   ei    = (const int*)d_in[1];
    const float* coord = (const float*)d_in[2];
    const float* lbox  = (const float*)d_in[4];
    const float* We1   = (const float*)d_in[5];
    const float* be1   = (const float*)d_in[6];
    const float* We2   = (const float*)d_in[7];
    const float* be2   = (const float*)d_in[8];
    const float* Wn1   = (const float*)d_in[9];
    const float* bn1   = (const float*)d_in[10];
    const float* Wn2   = (const float*)d_in[11];
    const float* bn2   = (const float*)d_in[12];

    const int N = in_sizes[0] / D;
    const int E = in_sizes[1] / 2;

    float* out       = (float*)d_out;
    float* h_out     = out;                       // [N,128]
    float* coord_out = out + (size_t)N * D;       // [N,3]
    float* ef_out    = coord_out + (size_t)N * 3; // [E,128]
    float* agg       = h_out;                     // in-place accumulator

    // zero the agg accumulator (h_out region) every launch
    hipMemsetAsync(h_out, 0, (size_t)N * D * sizeof(float), stream);

    coord_kernel<<<(N * 3 + 255) / 256, 256, 0, stream>>>(coord, lbox, coord_out, N * 3);

    edge_kernel<<<(E + EB - 1) / EB, 256, 0, stream>>>(
        h, ei, coord, lbox, We1, be1, We2, be2, ef_out, agg, E);

    node_kernel<<<(N + NB - 1) / NB, 256, 0, stream>>>(
        h, agg, Wn1, bn1, Wn2, bn2, h_out, N);
}

// Round 2
// 1175.666 us; speedup vs baseline: 1.2965x; 1.2965x over previous
//
#include <hip/hip_runtime.h>
#include <math.h>

#define D 128
#define SXS 264   // sX stride in bf16 elems (528B = 132 dwords == 4 mod 32 banks)
#define SHS 136   // sH1 stride

typedef unsigned int u32;
typedef unsigned short u16;
typedef __attribute__((ext_vector_type(8))) short bf16x8;
typedef __attribute__((ext_vector_type(4))) float f32x4;

__device__ __forceinline__ u16 f2bf(float f) {
    u32 u = __float_as_uint(f);
    return (u16)((u + 0x7FFFu + ((u >> 16) & 1u)) >> 16); // RNE
}
__device__ __forceinline__ float silu_f(float x) { return x / (1.0f + __expf(-x)); }

// ---------------- coord: out = remainder(coord, l) ----------------
__global__ void coord_kernel(const float* __restrict__ coord,
                             const float* __restrict__ lbox,
                             float* __restrict__ out, int n3) {
    int i = blockIdx.x * 256 + threadIdx.x;
    if (i < n3) {
        float ld = lbox[i % 3];
        float c = coord[i];
        float r = fmodf(c, ld);
        if (r < 0.f) r += ld;
        out[i] = r;
    }
}

// ---------------- weight prep: bf16 transposed Wt[n][k] into ws ----------------
// layout (bf16 elems): We1t [128][256] @0 | We2t [128][128] @32768 |
//                      Wn1t [128][256] @49152 | Wn2t [128][128] @81920   (total 98304)
__global__ void prep_weights(const float* __restrict__ We1, const float* __restrict__ We2,
                             const float* __restrict__ Wn1, const float* __restrict__ Wn2,
                             u16* __restrict__ wt) {
    int i = blockIdx.x * 256 + threadIdx.x;
    if (i < 32768)        { int n = i >> 8, k = i & 255;              wt[i] = f2bf(We1[(size_t)k*D + n]); }
    else if (i < 49152)   { int j = i - 32768; int n = j >> 7, k = j & 127; wt[i] = f2bf(We2[(size_t)k*D + n]); }
    else if (i < 81920)   { int j = i - 49152; int n = j >> 8, k = j & 255; wt[i] = f2bf(Wn1[(size_t)k*D + n]); }
    else if (i < 98304)   { int j = i - 81920; int n = j >> 7, k = j & 127; wt[i] = f2bf(Wn2[(size_t)k*D + n]); }
}

// ---------------- edge model (MFMA) + scatter-add ----------------
__global__ __launch_bounds__(256, 3) void edge_kernel(
    const float* __restrict__ h, const int* __restrict__ ei,
    const float* __restrict__ coord, const float* __restrict__ lbox,
    const u16* __restrict__ wt,
    const float* __restrict__ We1, const float* __restrict__ be1,
    const float* __restrict__ be2,
    float* __restrict__ ef_out, float* __restrict__ agg, int E)
{
    __shared__ __align__(16) u16 sX[64 * SXS];
    __shared__ __align__(16) u16 sH1[64 * SHS];
    __shared__ int srow[64], scol[64];
    __shared__ float sRad[64];

    const int t = threadIdx.x;
    const int lane = t & 63;
    const int wid = t >> 6;
    const int e0 = blockIdx.x * 64;

    if (t < 64) {
        int eg = e0 + t; if (eg >= E) eg = E - 1;
        srow[t] = ei[eg];
        scol[t] = ei[(size_t)E + eg];
    }
    __syncthreads();

    // stage X = [h[row] | h[col]] as bf16, plus radial
    {
        const int e = t & 63;
        const int q = t >> 6;
        const int r = srow[e], c = scol[e];
        const float4* src = (const float4*)((q < 2) ? (h + (size_t)r * D + q * 64)
                                                    : (h + (size_t)c * D + (q - 2) * 64));
        u16* dst = sX + e * SXS + q * 64;
        #pragma unroll
        for (int i = 0; i < 8; ++i) {
            float4 a = src[2 * i], b = src[2 * i + 1];
            u32 p0 = (u32)f2bf(a.x) | ((u32)f2bf(a.y) << 16);
            u32 p1 = (u32)f2bf(a.z) | ((u32)f2bf(a.w) << 16);
            u32 p2 = (u32)f2bf(b.x) | ((u32)f2bf(b.y) << 16);
            u32 p3 = (u32)f2bf(b.z) | ((u32)f2bf(b.w) << 16);
            *(uint4*)(dst + i * 8) = make_uint4(p0, p1, p2, p3);
        }
        if (t < 64) {
            int rr = srow[t], cc = scol[t];
            float rad = 0.f;
            #pragma unroll
            for (int d3 = 0; d3 < 3; ++d3) {
                float df = coord[(size_t)rr * 3 + d3] - coord[(size_t)cc * 3 + d3];
                float ld = lbox[d3];
                df = (df >  0.5f * ld) ? df - ld : df;
                df = (df < -0.5f * ld) ? df + ld : df;
                rad += df * df;
            }
            sRad[t] = rad;
        }
    }
    __syncthreads();

    const int lrow = lane & 15;
    const int lk = (lane >> 4) * 8;
    const int rbase = wid * 16;

    // ---- GEMM1: [64x256] @ We1t -> acc ----
    f32x4 acc[8] = {};
    {
        const u16* aP = sX + (rbase + lrow) * SXS + lk;
        const u16* bP = wt + lrow * 256 + lk;
        bf16x8 af = *(const bf16x8*)aP;
        bf16x8 bf[8];
        #pragma unroll
        for (int n = 0; n < 8; ++n) bf[n] = *(const bf16x8*)(bP + n * 4096);
        #pragma unroll 1
        for (int k0 = 0; k0 < 224; k0 += 32) {
            bf16x8 afn = *(const bf16x8*)(aP + k0 + 32);
            bf16x8 bfn[8];
            #pragma unroll
            for (int n = 0; n < 8; ++n) bfn[n] = *(const bf16x8*)(bP + n * 4096 + k0 + 32);
            #pragma unroll
            for (int n = 0; n < 8; ++n)
                acc[n] = __builtin_amdgcn_mfma_f32_16x16x32_bf16(af, bf[n], acc[n], 0, 0, 0);
            af = afn;
            #pragma unroll
            for (int n = 0; n < 8; ++n) bf[n] = bfn[n];
        }
        #pragma unroll
        for (int n = 0; n < 8; ++n)
            acc[n] = __builtin_amdgcn_mfma_f32_16x16x32_bf16(af, bf[n], acc[n], 0, 0, 0);
    }

    // rank-1 radial term + bias + SiLU -> sH1 (bf16)
    {
        const int g4 = (lane >> 4) * 4;
        float rd[4];
        #pragma unroll
        for (int r = 0; r < 4; ++r) rd[r] = sRad[rbase + g4 + r];
        #pragma unroll
        for (int n = 0; n < 8; ++n) {
            float wl = We1[(size_t)256 * D + n * 16 + lrow];
            float bb = be1[n * 16 + lrow];
            #pragma unroll
            for (int r = 0; r < 4; ++r) {
                float v = acc[n][r] + rd[r] * wl + bb;
                sH1[(rbase + g4 + r) * SHS + n * 16 + lrow] = f2bf(silu_f(v));
            }
        }
    }
    __syncthreads();

    // ---- GEMM2: [64x128] @ We2t ----
    f32x4 acc2[8] = {};
    {
        const u16* aP = sH1 + (rbase + lrow) * SHS + lk;
        const u16* bP = wt + 32768 + lrow * 128 + lk;
        bf16x8 af = *(const bf16x8*)aP;
        bf16x8 bf[8];
        #pragma unroll
        for (int n = 0; n < 8; ++n) bf[n] = *(const bf16x8*)(bP + n * 2048);
        #pragma unroll 1
        for (int k0 = 0; k0 < 96; k0 += 32) {
            bf16x8 afn = *(const bf16x8*)(aP + k0 + 32);
            bf16x8 bfn[8];
            #pragma unroll
            for (int n = 0; n < 8; ++n) bfn[n] = *(const bf16x8*)(bP + n * 2048 + k0 + 32);
            #pragma unroll
            for (int n = 0; n < 8; ++n)
                acc2[n] = __builtin_amdgcn_mfma_f32_16x16x32_bf16(af, bf[n], acc2[n], 0, 0, 0);
            af = afn;
            #pragma unroll
            for (int n = 0; n < 8; ++n) bf[n] = bfn[n];
        }
        #pragma unroll
        for (int n = 0; n < 8; ++n)
            acc2[n] = __builtin_amdgcn_mfma_f32_16x16x32_bf16(af, bf[n], acc2[n], 0, 0, 0);
    }

    // bias + SiLU -> f32 transpose buffer (reuse sX)
    float* sXf = (float*)sX;   // stride 132 f32
    {
        const int g4 = (lane >> 4) * 4;
        #pragma unroll
        for (int n = 0; n < 8; ++n) {
            float bb = be2[n * 16 + lrow];
            #pragma unroll
            for (int r = 0; r < 4; ++r)
                sXf[(rbase + g4 + r) * 132 + n * 16 + lrow] = silu_f(acc2[n][r] + bb);
        }
    }
    __syncthreads();

    // coalesced write-out + scatter-add
    {
        const int f4 = t & 31;
        const int eb = t >> 5;
        #pragma unroll
        for (int i = 0; i < 8; ++i) {
            int e = eb + i * 8;
            int eg = e0 + e;
            if (eg < E) {
                f32x4 v = *(const f32x4*)&sXf[e * 132 + f4 * 4];
                *(f32x4*)&ef_out[(size_t)eg * D + f4 * 4] = v;
                float* ap = agg + (size_t)srow[e] * D + f4 * 4;
                atomicAdd(ap + 0, v[0]);
                atomicAdd(ap + 1, v[1]);
                atomicAdd(ap + 2, v[2]);
                atomicAdd(ap + 3, v[3]);
            }
        }
    }
}

// ---------------- node model (MFMA, in-place agg -> h_out) ----------------
__global__ __launch_bounds__(256, 3) void node_kernel(
    const float* __restrict__ h, const float* __restrict__ agg,
    const u16* __restrict__ wt,
    const float* __restrict__ bn1, const float* __restrict__ bn2,
    float* __restrict__ h_out, int N)
{
    __shared__ __align__(16) u16 sX[64 * SXS];
    __shared__ __align__(16) u16 sH1[64 * SHS];

    const int t = threadIdx.x;
    const int lane = t & 63;
    const int wid = t >> 6;
    const int n0 = blockIdx.x * 64;

    // stage X = [h | agg] as bf16
    {
        const int e = t & 63;
        const int q = t >> 6;
        int ng = n0 + e; int ns = (ng < N) ? ng : N - 1;
        const float4* src = (const float4*)((q < 2) ? (h + (size_t)ns * D + q * 64)
                                                    : (agg + (size_t)ns * D + (q - 2) * 64));
        u16* dst = sX + e * SXS + q * 64;
        #pragma unroll
        for (int i = 0; i < 8; ++i) {
            float4 a = src[2 * i], b = src[2 * i + 1];
            u32 p0 = (u32)f2bf(a.x) | ((u32)f2bf(a.y) << 16);
            u32 p1 = (u32)f2bf(a.z) | ((u32)f2bf(a.w) << 16);
            u32 p2 = (u32)f2bf(b.x) | ((u32)f2bf(b.y) << 16);
            u32 p3 = (u32)f2bf(b.z) | ((u32)f2bf(b.w) << 16);
            *(uint4*)(dst + i * 8) = make_uint4(p0, p1, p2, p3);
        }
    }
    __syncthreads();

    const int lrow = lane & 15;
    const int lk = (lane >> 4) * 8;
    const int rbase = wid * 16;

    // ---- GEMM1: [64x256] @ Wn1t ----
    f32x4 acc[8] = {};
    {
        const u16* aP = sX + (rbase + lrow) * SXS + lk;
        const u16* bP = wt + 49152 + lrow * 256 + lk;
        bf16x8 af = *(const bf16x8*)aP;
        bf16x8 bf[8];
        #pragma unroll
        for (int n = 0; n < 8; ++n) bf[n] = *(const bf16x8*)(bP + n * 4096);
        #pragma unroll 1
        for (int k0 = 0; k0 < 224; k0 += 32) {
            bf16x8 afn = *(const bf16x8*)(aP + k0 + 32);
            bf16x8 bfn[8];
            #pragma unroll
            for (int n = 0; n < 8; ++n) bfn[n] = *(const bf16x8*)(bP + n * 4096 + k0 + 32);
            #pragma unroll
            for (int n = 0; n < 8; ++n)
                acc[n] = __builtin_amdgcn_mfma_f32_16x16x32_bf16(af, bf[n], acc[n], 0, 0, 0);
            af = afn;
            #pragma unroll
            for (int n = 0; n < 8; ++n) bf[n] = bfn[n];
        }
        #pragma unroll
        for (int n = 0; n < 8; ++n)
            acc[n] = __builtin_amdgcn_mfma_f32_16x16x32_bf16(af, bf[n], acc[n], 0, 0, 0);
    }

    // bias + SiLU -> sH1
    {
        const int g4 = (lane >> 4) * 4;
        #pragma unroll
        for (int n = 0; n < 8; ++n) {
            float bb = bn1[n * 16 + lrow];
            #pragma unroll
            for (int r = 0; r < 4; ++r)
                sH1[(rbase + g4 + r) * SHS + n * 16 + lrow] = f2bf(silu_f(acc[n][r] + bb));
        }
    }
    __syncthreads();

    // ---- GEMM2: [64x128] @ Wn2t ----
    f32x4 acc2[8] = {};
    {
        const u16* aP = sH1 + (rbase + lrow) * SHS + lk;
        const u16* bP = wt + 81920 + lrow * 128 + lk;
        bf16x8 af = *(const bf16x8*)aP;
        bf16x8 bf[8];
        #pragma unroll
        for (int n = 0; n < 8; ++n) bf[n] = *(const bf16x8*)(bP + n * 2048);
        #pragma unroll 1
        for (int k0 = 0; k0 < 96; k0 += 32) {
            bf16x8 afn = *(const bf16x8*)(aP + k0 + 32);
            bf16x8 bfn[8];
            #pragma unroll
            for (int n = 0; n < 8; ++n) bfn[n] = *(const bf16x8*)(bP + n * 2048 + k0 + 32);
            #pragma unroll
            for (int n = 0; n < 8; ++n)
                acc2[n] = __builtin_amdgcn_mfma_f32_16x16x32_bf16(af, bf[n], acc2[n], 0, 0, 0);
            af = afn;
            #pragma unroll
            for (int n = 0; n < 8; ++n) bf[n] = bfn[n];
        }
        #pragma unroll
        for (int n = 0; n < 8; ++n)
            acc2[n] = __builtin_amdgcn_mfma_f32_16x16x32_bf16(af, bf[n], acc2[n], 0, 0, 0);
    }

    // bias (no SiLU) -> f32 buffer
    float* sXf = (float*)sX;
    {
        const int g4 = (lane >> 4) * 4;
        #pragma unroll
        for (int n = 0; n < 8; ++n) {
            float bb = bn2[n * 16 + lrow];
            #pragma unroll
            for (int r = 0; r < 4; ++r)
                sXf[(rbase + g4 + r) * 132 + n * 16 + lrow] = acc2[n][r] + bb;
        }
    }
    __syncthreads();

    // residual + coalesced write
    {
        const int f4 = t & 31;
        const int nb = t >> 5;
        #pragma unroll
        for (int i = 0; i < 8; ++i) {
            int nl = nb + i * 8;
            int ng = n0 + nl;
            if (ng < N) {
                f32x4 v = *(const f32x4*)&sXf[nl * 132 + f4 * 4];
                const f32x4 hv = *(const f32x4*)&h[(size_t)ng * D + f4 * 4];
                v += hv;
                *(f32x4*)&h_out[(size_t)ng * D + f4 * 4] = v;
            }
        }
    }
}

extern "C" void kernel_launch(void* const* d_in, const int* in_sizes, int n_in,
                              void* d_out, int out_size, void* d_ws, size_t ws_size,
                              hipStream_t stream) {
    const float* h     = (const float*)d_in[0];
    const int*   ei    = (const int*)d_in[1];
    const float* coord = (const float*)d_in[2];
    const float* lbox  = (const float*)d_in[4];
    const float* We1   = (const float*)d_in[5];
    const float* be1   = (const float*)d_in[6];
    const float* We2   = (const float*)d_in[7];
    const float* be2   = (const float*)d_in[8];
    const float* Wn1   = (const float*)d_in[9];
    const float* bn1   = (const float*)d_in[10];
    const float* Wn2   = (const float*)d_in[11];
    const float* bn2   = (const float*)d_in[12];

    const int N = in_sizes[0] / D;
    const int E = in_sizes[1] / 2;

    float* out       = (float*)d_out;
    float* h_out     = out;                       // [N,128]
    float* coord_out = out + (size_t)N * D;       // [N,3]
    float* ef_out    = coord_out + (size_t)N * 3; // [E,128]
    float* agg       = h_out;                     // in-place accumulator

    u16* wt = (u16*)d_ws;                         // 196.6 KB of bf16 weights

    hipMemsetAsync(h_out, 0, (size_t)N * D * sizeof(float), stream);

    prep_weights<<<384, 256, 0, stream>>>(We1, We2, Wn1, Wn2, wt);

    coord_kernel<<<(N * 3 + 255) / 256, 256, 0, stream>>>(coord, lbox, coord_out, N * 3);

    edge_kernel<<<(E + 63) / 64, 256, 0, stream>>>(
        h, ei, coord, lbox, wt, We1, be1, be2, ef_out, agg, E);

    node_kernel<<<(N + 63) / 64, 256, 0, stream>>>(
        h, agg, wt, bn1, bn2, h_out, N);
}

// Round 3
// 742.776 us; speedup vs baseline: 2.0521x; 1.5828x over previous
//
#include <hip/hip_runtime.h>
#include <math.h>

#define D 128
#define SXS 264   // sX stride in bf16 elems (528B = 132 dwords == 4 mod 32 banks)
#define SHS 136   // sH1 stride

typedef unsigned int u32;
typedef unsigned short u16;
typedef __attribute__((ext_vector_type(8))) short bf16x8;
typedef __attribute__((ext_vector_type(4))) float f32x4;

__device__ __forceinline__ u16 f2bf(float f) {
    u32 u = __float_as_uint(f);
    return (u16)((u + 0x7FFFu + ((u >> 16) & 1u)) >> 16); // RNE
}
__device__ __forceinline__ float silu_f(float x) { return x / (1.0f + __expf(-x)); }

// ---------------- coord: out = remainder(coord, l) ----------------
__global__ void coord_kernel(const float* __restrict__ coord,
                             const float* __restrict__ lbox,
                             float* __restrict__ out, int n3) {
    int i = blockIdx.x * 256 + threadIdx.x;
    if (i < n3) {
        float ld = lbox[i % 3];
        float c = coord[i];
        float r = fmodf(c, ld);
        if (r < 0.f) r += ld;
        out[i] = r;
    }
}

// ---------------- weight prep: bf16 transposed Wt[n][k] into ws ----------------
__global__ void prep_weights(const float* __restrict__ We1, const float* __restrict__ We2,
                             const float* __restrict__ Wn1, const float* __restrict__ Wn2,
                             u16* __restrict__ wt) {
    int i = blockIdx.x * 256 + threadIdx.x;
    if (i < 32768)        { int n = i >> 8, k = i & 255;              wt[i] = f2bf(We1[(size_t)k*D + n]); }
    else if (i < 49152)   { int j = i - 32768; int n = j >> 7, k = j & 127; wt[i] = f2bf(We2[(size_t)k*D + n]); }
    else if (i < 81920)   { int j = i - 49152; int n = j >> 8, k = j & 255; wt[i] = f2bf(Wn1[(size_t)k*D + n]); }
    else if (i < 98304)   { int j = i - 81920; int n = j >> 7, k = j & 127; wt[i] = f2bf(Wn2[(size_t)k*D + n]); }
}

// ---------------- CSR build ----------------
__global__ void hist_kernel(const int* __restrict__ ei, int* __restrict__ cnt, int E) {
    int e = blockIdx.x * 256 + threadIdx.x;
    if (e < E) atomicAdd(&cnt[ei[e]], 1);
}

// 256 thr/block, 1024 elems/block; exclusive scan within block + block sums
__global__ void scan1_kernel(const int* __restrict__ cnt, int* __restrict__ offs,
                             int* __restrict__ bsum, int n /* = N+1 */) {
    __shared__ int s[256];
    int t = threadIdx.x, b = blockIdx.x;
    int base = b * 1024 + t * 4;
    int v[4];
    #pragma unroll
    for (int i = 0; i < 4; ++i) { int idx = base + i; v[i] = (idx < n - 1) ? cnt[idx] : 0; }
    int lsum = v[0] + v[1] + v[2] + v[3];
    s[t] = lsum; __syncthreads();
    #pragma unroll
    for (int off = 1; off < 256; off <<= 1) {
        int x = (t >= off) ? s[t - off] : 0; __syncthreads();
        s[t] += x; __syncthreads();
    }
    int run = s[t] - lsum;
    #pragma unroll
    for (int i = 0; i < 4; ++i) { int idx = base + i; if (idx < n) offs[idx] = run; run += v[i]; }
    if (t == 255) bsum[b] = s[255];
}

__global__ void scan2_kernel(int* __restrict__ bsum, int nb) {
    __shared__ int s[64];
    int t = threadIdx.x;
    int orig = (t < nb) ? bsum[t] : 0;
    s[t] = orig; __syncthreads();
    #pragma unroll
    for (int off = 1; off < 64; off <<= 1) {
        int x = (t >= off) ? s[t - off] : 0; __syncthreads();
        s[t] += x; __syncthreads();
    }
    if (t < nb) bsum[t] = s[t] - orig;
}

// offs[i] += bsum[block]; cursor[i] = offs[i] (cursor aliases cnt, safe: cnt no longer needed)
__global__ void scan3_kernel(int* __restrict__ offs, const int* __restrict__ bsum,
                             int* __restrict__ cursor, int n) {
    int i = blockIdx.x * 256 + threadIdx.x;
    if (i < n) {
        int v = offs[i] + bsum[i >> 10];
        offs[i] = v;
        if (i < n - 1) cursor[i] = v;
    }
}

__global__ void scatter_kernel(const int* __restrict__ ei, int* __restrict__ cursor,
                               int* __restrict__ perm, int E) {
    int e = blockIdx.x * 256 + threadIdx.x;
    if (e < E) { int p = atomicAdd(&cursor[ei[e]], 1); perm[p] = e; }
}

// ---------------- gather-reduce aggregation: one wave per node ----------------
__global__ __launch_bounds__(256) void agg_kernel(const float* __restrict__ ef,
                                                  const int* __restrict__ offs,
                                                  const int* __restrict__ perm,
                                                  float* __restrict__ agg, int N) {
    const int wid = threadIdx.x >> 6, lane = threadIdx.x & 63;
    const int node = blockIdx.x * 4 + wid;
    if (node >= N) return;
    const int s = offs[node], e = offs[node + 1];
    float ax = 0.f, ay = 0.f;
    for (int p = s; p < e; ++p) {
        int ed = perm[p];
        float2 v = ((const float2*)(ef + (size_t)ed * D))[lane];
        ax += v.x; ay += v.y;
    }
    ((float2*)(agg + (size_t)node * D))[lane] = make_float2(ax, ay);
}

// ---------------- edge model (MFMA), no atomics ----------------
__global__ __launch_bounds__(256, 3) void edge_kernel(
    const float* __restrict__ h, const int* __restrict__ ei,
    const float* __restrict__ coord, const float* __restrict__ lbox,
    const u16* __restrict__ wt,
    const float* __restrict__ We1, const float* __restrict__ be1,
    const float* __restrict__ be2,
    float* __restrict__ ef_out, int E)
{
    __shared__ __align__(16) u16 sX[64 * SXS];
    __shared__ __align__(16) u16 sH1[64 * SHS];
    __shared__ int srow[64], scol[64];
    __shared__ float sRad[64];

    const int t = threadIdx.x;
    const int lane = t & 63;
    const int wid = t >> 6;
    const int e0 = blockIdx.x * 64;

    if (t < 64) {
        int eg = e0 + t; if (eg >= E) eg = E - 1;
        srow[t] = ei[eg];
        scol[t] = ei[(size_t)E + eg];
    }
    __syncthreads();

    // stage X = [h[row] | h[col]] as bf16, plus radial
    {
        const int e = t & 63;
        const int q = t >> 6;
        const int r = srow[e], c = scol[e];
        const float4* src = (const float4*)((q < 2) ? (h + (size_t)r * D + q * 64)
                                                    : (h + (size_t)c * D + (q - 2) * 64));
        u16* dst = sX + e * SXS + q * 64;
        #pragma unroll
        for (int i = 0; i < 8; ++i) {
            float4 a = src[2 * i], b = src[2 * i + 1];
            u32 p0 = (u32)f2bf(a.x) | ((u32)f2bf(a.y) << 16);
            u32 p1 = (u32)f2bf(a.z) | ((u32)f2bf(a.w) << 16);
            u32 p2 = (u32)f2bf(b.x) | ((u32)f2bf(b.y) << 16);
            u32 p3 = (u32)f2bf(b.z) | ((u32)f2bf(b.w) << 16);
            *(uint4*)(dst + i * 8) = make_uint4(p0, p1, p2, p3);
        }
        if (t < 64) {
            int rr = srow[t], cc = scol[t];
            float rad = 0.f;
            #pragma unroll
            for (int d3 = 0; d3 < 3; ++d3) {
                float df = coord[(size_t)rr * 3 + d3] - coord[(size_t)cc * 3 + d3];
                float ld = lbox[d3];
                df = (df >  0.5f * ld) ? df - ld : df;
                df = (df < -0.5f * ld) ? df + ld : df;
                rad += df * df;
            }
            sRad[t] = rad;
        }
    }
    __syncthreads();

    const int lrow = lane & 15;
    const int lk = (lane >> 4) * 8;
    const int rbase = wid * 16;

    // ---- GEMM1: [64x256] @ We1t -> acc ----
    f32x4 acc[8] = {};
    {
        const u16* aP = sX + (rbase + lrow) * SXS + lk;
        const u16* bP = wt + lrow * 256 + lk;
        bf16x8 af = *(const bf16x8*)aP;
        bf16x8 bf[8];
        #pragma unroll
        for (int n = 0; n < 8; ++n) bf[n] = *(const bf16x8*)(bP + n * 4096);
        #pragma unroll 1
        for (int k0 = 0; k0 < 224; k0 += 32) {
            bf16x8 afn = *(const bf16x8*)(aP + k0 + 32);
            bf16x8 bfn[8];
            #pragma unroll
            for (int n = 0; n < 8; ++n) bfn[n] = *(const bf16x8*)(bP + n * 4096 + k0 + 32);
            #pragma unroll
            for (int n = 0; n < 8; ++n)
                acc[n] = __builtin_amdgcn_mfma_f32_16x16x32_bf16(af, bf[n], acc[n], 0, 0, 0);
            af = afn;
            #pragma unroll
            for (int n = 0; n < 8; ++n) bf[n] = bfn[n];
        }
        #pragma unroll
        for (int n = 0; n < 8; ++n)
            acc[n] = __builtin_amdgcn_mfma_f32_16x16x32_bf16(af, bf[n], acc[n], 0, 0, 0);
    }

    // rank-1 radial term + bias + SiLU -> sH1 (bf16)
    {
        const int g4 = (lane >> 4) * 4;
        float rd[4];
        #pragma unroll
        for (int r = 0; r < 4; ++r) rd[r] = sRad[rbase + g4 + r];
        #pragma unroll
        for (int n = 0; n < 8; ++n) {
            float wl = We1[(size_t)256 * D + n * 16 + lrow];
            float bb = be1[n * 16 + lrow];
            #pragma unroll
            for (int r = 0; r < 4; ++r) {
                float v = acc[n][r] + rd[r] * wl + bb;
                sH1[(rbase + g4 + r) * SHS + n * 16 + lrow] = f2bf(silu_f(v));
            }
        }
    }
    __syncthreads();

    // ---- GEMM2: [64x128] @ We2t ----
    f32x4 acc2[8] = {};
    {
        const u16* aP = sH1 + (rbase + lrow) * SHS + lk;
        const u16* bP = wt + 32768 + lrow * 128 + lk;
        bf16x8 af = *(const bf16x8*)aP;
        bf16x8 bf[8];
        #pragma unroll
        for (int n = 0; n < 8; ++n) bf[n] = *(const bf16x8*)(bP + n * 2048);
        #pragma unroll 1
        for (int k0 = 0; k0 < 96; k0 += 32) {
            bf16x8 afn = *(const bf16x8*)(aP + k0 + 32);
            bf16x8 bfn[8];
            #pragma unroll
            for (int n = 0; n < 8; ++n) bfn[n] = *(const bf16x8*)(bP + n * 2048 + k0 + 32);
            #pragma unroll
            for (int n = 0; n < 8; ++n)
                acc2[n] = __builtin_amdgcn_mfma_f32_16x16x32_bf16(af, bf[n], acc2[n], 0, 0, 0);
            af = afn;
            #pragma unroll
            for (int n = 0; n < 8; ++n) bf[n] = bfn[n];
        }
        #pragma unroll
        for (int n = 0; n < 8; ++n)
            acc2[n] = __builtin_amdgcn_mfma_f32_16x16x32_bf16(af, bf[n], acc2[n], 0, 0, 0);
    }

    // bias + SiLU -> f32 transpose buffer (reuse sX)
    float* sXf = (float*)sX;   // stride 132 f32
    {
        const int g4 = (lane >> 4) * 4;
        #pragma unroll
        for (int n = 0; n < 8; ++n) {
            float bb = be2[n * 16 + lrow];
            #pragma unroll
            for (int r = 0; r < 4; ++r)
                sXf[(rbase + g4 + r) * 132 + n * 16 + lrow] = silu_f(acc2[n][r] + bb);
        }
    }
    __syncthreads();

    // coalesced write-out
    {
        const int f4 = t & 31;
        const int eb = t >> 5;
        #pragma unroll
        for (int i = 0; i < 8; ++i) {
            int e = eb + i * 8;
            int eg = e0 + e;
            if (eg < E) {
                f32x4 v = *(const f32x4*)&sXf[e * 132 + f4 * 4];
                *(f32x4*)&ef_out[(size_t)eg * D + f4 * 4] = v;
            }
        }
    }
}

// ---------------- node model (MFMA, in-place agg -> h_out) ----------------
__global__ __launch_bounds__(256, 3) void node_kernel(
    const float* __restrict__ h, const float* __restrict__ agg,
    const u16* __restrict__ wt,
    const float* __restrict__ bn1, const float* __restrict__ bn2,
    float* __restrict__ h_out, int N)
{
    __shared__ __align__(16) u16 sX[64 * SXS];
    __shared__ __align__(16) u16 sH1[64 * SHS];

    const int t = threadIdx.x;
    const int lane = t & 63;
    const int wid = t >> 6;
    const int n0 = blockIdx.x * 64;

    {
        const int e = t & 63;
        const int q = t >> 6;
        int ng = n0 + e; int ns = (ng < N) ? ng : N - 1;
        const float4* src = (const float4*)((q < 2) ? (h + (size_t)ns * D + q * 64)
                                                    : (agg + (size_t)ns * D + (q - 2) * 64));
        u16* dst = sX + e * SXS + q * 64;
        #pragma unroll
        for (int i = 0; i < 8; ++i) {
            float4 a = src[2 * i], b = src[2 * i + 1];
            u32 p0 = (u32)f2bf(a.x) | ((u32)f2bf(a.y) << 16);
            u32 p1 = (u32)f2bf(a.z) | ((u32)f2bf(a.w) << 16);
            u32 p2 = (u32)f2bf(b.x) | ((u32)f2bf(b.y) << 16);
            u32 p3 = (u32)f2bf(b.z) | ((u32)f2bf(b.w) << 16);
            *(uint4*)(dst + i * 8) = make_uint4(p0, p1, p2, p3);
        }
    }
    __syncthreads();

    const int lrow = lane & 15;
    const int lk = (lane >> 4) * 8;
    const int rbase = wid * 16;

    f32x4 acc[8] = {};
    {
        const u16* aP = sX + (rbase + lrow) * SXS + lk;
        const u16* bP = wt + 49152 + lrow * 256 + lk;
        bf16x8 af = *(const bf16x8*)aP;
        bf16x8 bf[8];
        #pragma unroll
        for (int n = 0; n < 8; ++n) bf[n] = *(const bf16x8*)(bP + n * 4096);
        #pragma unroll 1
        for (int k0 = 0; k0 < 224; k0 += 32) {
            bf16x8 afn = *(const bf16x8*)(aP + k0 + 32);
            bf16x8 bfn[8];
            #pragma unroll
            for (int n = 0; n < 8; ++n) bfn[n] = *(const bf16x8*)(bP + n * 4096 + k0 + 32);
            #pragma unroll
            for (int n = 0; n < 8; ++n)
                acc[n] = __builtin_amdgcn_mfma_f32_16x16x32_bf16(af, bf[n], acc[n], 0, 0, 0);
            af = afn;
            #pragma unroll
            for (int n = 0; n < 8; ++n) bf[n] = bfn[n];
        }
        #pragma unroll
        for (int n = 0; n < 8; ++n)
            acc[n] = __builtin_amdgcn_mfma_f32_16x16x32_bf16(af, bf[n], acc[n], 0, 0, 0);
    }

    {
        const int g4 = (lane >> 4) * 4;
        #pragma unroll
        for (int n = 0; n < 8; ++n) {
            float bb = bn1[n * 16 + lrow];
            #pragma unroll
            for (int r = 0; r < 4; ++r)
                sH1[(rbase + g4 + r) * SHS + n * 16 + lrow] = f2bf(silu_f(acc[n][r] + bb));
        }
    }
    __syncthreads();

    f32x4 acc2[8] = {};
    {
        const u16* aP = sH1 + (rbase + lrow) * SHS + lk;
        const u16* bP = wt + 81920 + lrow * 128 + lk;
        bf16x8 af = *(const bf16x8*)aP;
        bf16x8 bf[8];
        #pragma unroll
        for (int n = 0; n < 8; ++n) bf[n] = *(const bf16x8*)(bP + n * 2048);
        #pragma unroll 1
        for (int k0 = 0; k0 < 96; k0 += 32) {
            bf16x8 afn = *(const bf16x8*)(aP + k0 + 32);
            bf16x8 bfn[8];
            #pragma unroll
            for (int n = 0; n < 8; ++n) bfn[n] = *(const bf16x8*)(bP + n * 2048 + k0 + 32);
            #pragma unroll
            for (int n = 0; n < 8; ++n)
                acc2[n] = __builtin_amdgcn_mfma_f32_16x16x32_bf16(af, bf[n], acc2[n], 0, 0, 0);
            af = afn;
            #pragma unroll
            for (int n = 0; n < 8; ++n) bf[n] = bfn[n];
        }
        #pragma unroll
        for (int n = 0; n < 8; ++n)
            acc2[n] = __builtin_amdgcn_mfma_f32_16x16x32_bf16(af, bf[n], acc2[n], 0, 0, 0);
    }

    float* sXf = (float*)sX;
    {
        const int g4 = (lane >> 4) * 4;
        #pragma unroll
        for (int n = 0; n < 8; ++n) {
            float bb = bn2[n * 16 + lrow];
            #pragma unroll
            for (int r = 0; r < 4; ++r)
                sXf[(rbase + g4 + r) * 132 + n * 16 + lrow] = acc2[n][r] + bb;
        }
    }
    __syncthreads();

    {
        const int f4 = t & 31;
        const int nb = t >> 5;
        #pragma unroll
        for (int i = 0; i < 8; ++i) {
            int nl = nb + i * 8;
            int ng = n0 + nl;
            if (ng < N) {
                f32x4 v = *(const f32x4*)&sXf[nl * 132 + f4 * 4];
                const f32x4 hv = *(const f32x4*)&h[(size_t)ng * D + f4 * 4];
                v += hv;
                *(f32x4*)&h_out[(size_t)ng * D + f4 * 4] = v;
            }
        }
    }
}

extern "C" void kernel_launch(void* const* d_in, const int* in_sizes, int n_in,
                              void* d_out, int out_size, void* d_ws, size_t ws_size,
                              hipStream_t stream) {
    const float* h     = (const float*)d_in[0];
    const int*   ei    = (const int*)d_in[1];
    const float* coord = (const float*)d_in[2];
    const float* lbox  = (const float*)d_in[4];
    const float* We1   = (const float*)d_in[5];
    const float* be1   = (const float*)d_in[6];
    const float* We2   = (const float*)d_in[7];
    const float* be2   = (const float*)d_in[8];
    const float* Wn1   = (const float*)d_in[9];
    const float* bn1   = (const float*)d_in[10];
    const float* Wn2   = (const float*)d_in[11];
    const float* bn2   = (const float*)d_in[12];

    const int N = in_sizes[0] / D;
    const int E = in_sizes[1] / 2;

    float* out       = (float*)d_out;
    float* h_out     = out;                       // [N,128]
    float* coord_out = out + (size_t)N * D;       // [N,3]
    float* ef_out    = coord_out + (size_t)N * 3; // [E,128]
    float* agg       = h_out;                     // agg lives in h_out region

    // workspace layout (ints)
    int* wsi = (int*)d_ws;
    u16* wt     = (u16*)d_ws;                     // 98304 u16 = 49152 ints
    int* offs   = wsi + 49152;                    // N+1
    int* cursor = offs + (N + 8);                 // N (aliases "cnt")
    int* bsum   = cursor + (N + 8);               // 64
    int* perm   = bsum + 64;                      // E

    const int nb1 = (N + 1 + 1023) / 1024;        // scan1 blocks (<=64)

    prep_weights<<<384, 256, 0, stream>>>(We1, We2, Wn1, Wn2, wt);
    coord_kernel<<<(N * 3 + 255) / 256, 256, 0, stream>>>(coord, lbox, coord_out, N * 3);

    // CSR build
    hipMemsetAsync(cursor, 0, (size_t)N * sizeof(int), stream);
    hist_kernel<<<(E + 255) / 256, 256, 0, stream>>>(ei, cursor, E);
    scan1_kernel<<<nb1, 256, 0, stream>>>(cursor, offs, bsum, N + 1);
    scan2_kernel<<<1, 64, 0, stream>>>(bsum, nb1);
    scan3_kernel<<<(N + 1 + 255) / 256, 256, 0, stream>>>(offs, bsum, cursor, N + 1);
    scatter_kernel<<<(E + 255) / 256, 256, 0, stream>>>(ei, cursor, perm, E);

    edge_kernel<<<(E + 63) / 64, 256, 0, stream>>>(
        h, ei, coord, lbox, wt, We1, be1, be2, ef_out, E);

    agg_kernel<<<(N + 3) / 4, 256, 0, stream>>>(ef_out, offs, perm, agg, N);

    node_kernel<<<(N + 63) / 64, 256, 0, stream>>>(
        h, agg, wt, bn1, bn2, h_out, N);
}

// Round 4
// 416.983 us; speedup vs baseline: 3.6554x; 1.7813x over previous
//
#include <hip/hip_runtime.h>
#include <math.h>

#define D 128
#define SXS 264   // sX stride in bf16 elems
#define SHS 136   // sH1 stride

typedef unsigned int u32;
typedef unsigned short u16;
typedef __attribute__((ext_vector_type(8))) short bf16x8;
typedef __attribute__((ext_vector_type(4))) float f32x4;

__device__ __forceinline__ u16 f2bf(float f) {
    u32 u = __float_as_uint(f);
    return (u16)((u + 0x7FFFu + ((u >> 16) & 1u)) >> 16); // RNE
}
__device__ __forceinline__ float silu_f(float x) { return x / (1.0f + __expf(-x)); }

// ---------------- coord: out = remainder(coord, l) ----------------
__global__ void coord_kernel(const float* __restrict__ coord,
                             const float* __restrict__ lbox,
                             float* __restrict__ out, int n3) {
    int i = blockIdx.x * 256 + threadIdx.x;
    if (i < n3) {
        float ld = lbox[i % 3];
        float c = coord[i];
        float r = fmodf(c, ld);
        if (r < 0.f) r += ld;
        out[i] = r;
    }
}

// ---------------- weight prep: bf16 transposed Wt[n][k] into ws ----------------
__global__ void prep_weights(const float* __restrict__ We1, const float* __restrict__ We2,
                             const float* __restrict__ Wn1, const float* __restrict__ Wn2,
                             u16* __restrict__ wt) {
    int i = blockIdx.x * 256 + threadIdx.x;
    if (i < 32768)        { int n = i >> 8, k = i & 255;              wt[i] = f2bf(We1[(size_t)k*D + n]); }
    else if (i < 49152)   { int j = i - 32768; int n = j >> 7, k = j & 127; wt[i] = f2bf(We2[(size_t)k*D + n]); }
    else if (i < 81920)   { int j = i - 49152; int n = j >> 8, k = j & 255; wt[i] = f2bf(Wn1[(size_t)k*D + n]); }
    else if (i < 98304)   { int j = i - 81920; int n = j >> 7, k = j & 127; wt[i] = f2bf(Wn2[(size_t)k*D + n]); }
}

// ---------------- h -> bf16 copy ----------------
__global__ void prep_h16(const float* __restrict__ h, u16* __restrict__ h16, int total8) {
    int i = blockIdx.x * 256 + threadIdx.x;
    if (i < total8) {
        const float4* s = (const float4*)(h + (size_t)i * 8);
        float4 a = s[0], b = s[1];
        u32 p0 = (u32)f2bf(a.x) | ((u32)f2bf(a.y) << 16);
        u32 p1 = (u32)f2bf(a.z) | ((u32)f2bf(a.w) << 16);
        u32 p2 = (u32)f2bf(b.x) | ((u32)f2bf(b.y) << 16);
        u32 p3 = (u32)f2bf(b.z) | ((u32)f2bf(b.w) << 16);
        *(uint4*)(h16 + (size_t)i * 8) = make_uint4(p0, p1, p2, p3);
    }
}

// ---------------- CSR build ----------------
__global__ void hist_kernel(const int* __restrict__ ei, int* __restrict__ cnt, int E) {
    int e = blockIdx.x * 256 + threadIdx.x;
    if (e < E) atomicAdd(&cnt[ei[e]], 1);
}

__global__ void scan1_kernel(const int* __restrict__ cnt, int* __restrict__ offs,
                             int* __restrict__ bsum, int n /* = N+1 */) {
    __shared__ int s[256];
    int t = threadIdx.x, b = blockIdx.x;
    int base = b * 1024 + t * 4;
    int v[4];
    #pragma unroll
    for (int i = 0; i < 4; ++i) { int idx = base + i; v[i] = (idx < n - 1) ? cnt[idx] : 0; }
    int lsum = v[0] + v[1] + v[2] + v[3];
    s[t] = lsum; __syncthreads();
    #pragma unroll
    for (int off = 1; off < 256; off <<= 1) {
        int x = (t >= off) ? s[t - off] : 0; __syncthreads();
        s[t] += x; __syncthreads();
    }
    int run = s[t] - lsum;
    #pragma unroll
    for (int i = 0; i < 4; ++i) { int idx = base + i; if (idx < n) offs[idx] = run; run += v[i]; }
    if (t == 255) bsum[b] = s[255];
}

__global__ void scan2_kernel(int* __restrict__ bsum, int nb) {
    __shared__ int s[64];
    int t = threadIdx.x;
    int orig = (t < nb) ? bsum[t] : 0;
    s[t] = orig; __syncthreads();
    #pragma unroll
    for (int off = 1; off < 64; off <<= 1) {
        int x = (t >= off) ? s[t - off] : 0; __syncthreads();
        s[t] += x; __syncthreads();
    }
    if (t < nb) bsum[t] = s[t] - orig;
}

__global__ void scan3_kernel(int* __restrict__ offs, const int* __restrict__ bsum,
                             int* __restrict__ cursor, int n) {
    int i = blockIdx.x * 256 + threadIdx.x;
    if (i < n) {
        int v = offs[i] + bsum[i >> 10];
        offs[i] = v;
        if (i < n - 1) cursor[i] = v;
    }
}

__global__ void scatter_kernel(const int* __restrict__ ei, int* __restrict__ cursor,
                               int* __restrict__ perm, int E) {
    int e = blockIdx.x * 256 + threadIdx.x;
    if (e < E) { int p = atomicAdd(&cursor[ei[e]], 1); perm[p] = e; }
}

// ---------------- gather-reduce aggregation: one wave per node ----------------
__global__ __launch_bounds__(256) void agg_kernel(const float* __restrict__ ef,
                                                  const int* __restrict__ offs,
                                                  const int* __restrict__ perm,
                                                  u16* __restrict__ agg16,
                                                  float* __restrict__ aggf, int N) {
    const int wid = threadIdx.x >> 6, lane = threadIdx.x & 63;
    const int node = blockIdx.x * 4 + wid;
    if (node >= N) return;
    const int s = offs[node], e = offs[node + 1];
    float ax = 0.f, ay = 0.f;
    for (int p = s; p < e; ++p) {
        int ed = perm[p];
        float2 v = ((const float2*)(ef + (size_t)ed * D))[lane];
        ax += v.x; ay += v.y;
    }
    if (agg16) {
        u32 pk = (u32)f2bf(ax) | ((u32)f2bf(ay) << 16);
        ((u32*)(agg16 + (size_t)node * D))[lane] = pk;
    } else {
        ((float2*)(aggf + (size_t)node * D))[lane] = make_float2(ax, ay);
    }
}

// ---------------- edge model (MFMA; n-partitioned waves, B in regs) ----------------
__global__ __launch_bounds__(256, 3) void edge_kernel(
    const float* __restrict__ h, const u16* __restrict__ h16,
    const int* __restrict__ ei,
    const float* __restrict__ coord, const float* __restrict__ lbox,
    const u16* __restrict__ wt,
    const float* __restrict__ We1, const float* __restrict__ be1,
    const float* __restrict__ be2,
    float* __restrict__ ef_out, int E)
{
    __shared__ __align__(16) u16 sX[64 * SXS];
    __shared__ __align__(16) u16 sH1[64 * SHS];
    __shared__ int srow[64], scol[64];
    __shared__ float sRad[64];

    const int t = threadIdx.x;
    const int lane = t & 63;
    const int wid = t >> 6;
    const int e0 = blockIdx.x * 64;

    if (t < 64) {
        int eg = e0 + t; if (eg >= E) eg = E - 1;
        srow[t] = ei[eg];
        scol[t] = ei[(size_t)E + eg];
    }
    __syncthreads();

    // stage X = [h[row] | h[col]] as bf16, plus radial
    {
        const int e = t & 63;
        const int q = t >> 6;
        const int r = srow[e], c = scol[e];
        u16* dst = sX + e * SXS + q * 64;
        if (h16) {
            const u16* src = h16 + (size_t)((q < 2) ? r : c) * D + (q & 1) * 64;
            #pragma unroll
            for (int i = 0; i < 8; ++i)
                *(uint4*)(dst + i * 8) = *(const uint4*)(src + i * 8);
        } else {
            const float4* src = (const float4*)((q < 2) ? (h + (size_t)r * D + (q & 1) * 64)
                                                        : (h + (size_t)c * D + (q & 1) * 64));
            #pragma unroll
            for (int i = 0; i < 8; ++i) {
                float4 a = src[2 * i], b = src[2 * i + 1];
                u32 p0 = (u32)f2bf(a.x) | ((u32)f2bf(a.y) << 16);
                u32 p1 = (u32)f2bf(a.z) | ((u32)f2bf(a.w) << 16);
                u32 p2 = (u32)f2bf(b.x) | ((u32)f2bf(b.y) << 16);
                u32 p3 = (u32)f2bf(b.z) | ((u32)f2bf(b.w) << 16);
                *(uint4*)(dst + i * 8) = make_uint4(p0, p1, p2, p3);
            }
        }
        if (t < 64) {
            int rr = srow[t], cc = scol[t];
            float rad = 0.f;
            #pragma unroll
            for (int d3 = 0; d3 < 3; ++d3) {
                float df = coord[(size_t)rr * 3 + d3] - coord[(size_t)cc * 3 + d3];
                float ld = lbox[d3];
                df = (df >  0.5f * ld) ? df - ld : df;
                df = (df < -0.5f * ld) ? df + ld : df;
                rad += df * df;
            }
            sRad[t] = rad;
        }
    }
    __syncthreads();

    const int lrow = lane & 15;
    const int kg = lane >> 4;
    const int g4 = kg * 4;
    const int nbase = wid * 32;

    // ---- GEMM1: all 64 edges x out-slice [nbase, nbase+32), K=256 ----
    f32x4 acc[4][2] = {};
    {
        bf16x8 B1[16];
        #pragma unroll
        for (int nn = 0; nn < 2; ++nn)
            #pragma unroll
            for (int s = 0; s < 8; ++s)
                B1[nn * 8 + s] = *(const bf16x8*)(wt + (size_t)(nbase + nn * 16 + lrow) * 256 + s * 32 + kg * 8);

        #pragma unroll
        for (int s = 0; s < 8; ++s) {
            bf16x8 a[4];
            #pragma unroll
            for (int m = 0; m < 4; ++m)
                a[m] = *(const bf16x8*)(sX + (m * 16 + lrow) * SXS + s * 32 + kg * 8);
            #pragma unroll
            for (int m = 0; m < 4; ++m)
                #pragma unroll
                for (int nn = 0; nn < 2; ++nn)
                    acc[m][nn] = __builtin_amdgcn_mfma_f32_16x16x32_bf16(a[m], B1[nn * 8 + s], acc[m][nn], 0, 0, 0);
        }
    }

    // rank-1 radial + bias + SiLU -> sH1 (bf16)
    #pragma unroll
    for (int nn = 0; nn < 2; ++nn) {
        int out = nbase + nn * 16 + lrow;
        float wl = We1[(size_t)256 * D + out];
        float bb = be1[out];
        #pragma unroll
        for (int m = 0; m < 4; ++m) {
            #pragma unroll
            for (int r = 0; r < 4; ++r) {
                int e = m * 16 + g4 + r;
                float v = acc[m][nn][r] + sRad[e] * wl + bb;
                sH1[e * SHS + out] = f2bf(silu_f(v));
            }
        }
    }
    __syncthreads();

    // ---- GEMM2: K=128 ----
    f32x4 acc2[4][2] = {};
    {
        bf16x8 B2[8];
        #pragma unroll
        for (int nn = 0; nn < 2; ++nn)
            #pragma unroll
            for (int s = 0; s < 4; ++s)
                B2[nn * 4 + s] = *(const bf16x8*)(wt + 32768 + (size_t)(nbase + nn * 16 + lrow) * 128 + s * 32 + kg * 8);

        #pragma unroll
        for (int s = 0; s < 4; ++s) {
            bf16x8 a[4];
            #pragma unroll
            for (int m = 0; m < 4; ++m)
                a[m] = *(const bf16x8*)(sH1 + (m * 16 + lrow) * SHS + s * 32 + kg * 8);
            #pragma unroll
            for (int m = 0; m < 4; ++m)
                #pragma unroll
                for (int nn = 0; nn < 2; ++nn)
                    acc2[m][nn] = __builtin_amdgcn_mfma_f32_16x16x32_bf16(a[m], B2[nn * 4 + s], acc2[m][nn], 0, 0, 0);
        }
    }
    __syncthreads();   // all waves done reading sX (GEMM1) and sH1 before sXf overwrite

    // bias + SiLU -> f32 transpose buffer (reuse sX)
    float* sXf = (float*)sX;   // stride 132 f32
    #pragma unroll
    for (int nn = 0; nn < 2; ++nn) {
        int out = nbase + nn * 16 + lrow;
        float bb = be2[out];
        #pragma unroll
        for (int m = 0; m < 4; ++m)
            #pragma unroll
            for (int r = 0; r < 4; ++r)
                sXf[(m * 16 + g4 + r) * 132 + out] = silu_f(acc2[m][nn][r] + bb);
    }
    __syncthreads();

    // coalesced write-out
    {
        const int f4 = t & 31;
        const int eb = t >> 5;
        #pragma unroll
        for (int i = 0; i < 8; ++i) {
            int e = eb + i * 8;
            int eg = e0 + e;
            if (eg < E)
                *(f32x4*)&ef_out[(size_t)eg * D + f4 * 4] = *(const f32x4*)&sXf[e * 132 + f4 * 4];
        }
    }
}

// ---------------- node model (MFMA; n-partitioned waves, B in regs) ----------------
__global__ __launch_bounds__(256, 3) void node_kernel(
    const float* __restrict__ h, const u16* __restrict__ h16,
    const float* __restrict__ aggf, const u16* __restrict__ agg16,
    const u16* __restrict__ wt,
    const float* __restrict__ bn1, const float* __restrict__ bn2,
    float* __restrict__ h_out, int N)
{
    __shared__ __align__(16) u16 sX[64 * SXS];
    __shared__ __align__(16) u16 sH1[64 * SHS];

    const int t = threadIdx.x;
    const int lane = t & 63;
    const int wid = t >> 6;
    const int n0 = blockIdx.x * 64;

    {
        const int e = t & 63;
        const int q = t >> 6;
        int ng = n0 + e; int ns = (ng < N) ? ng : N - 1;
        u16* dst = sX + e * SXS + q * 64;
        if (h16) {
            const u16* src = ((q < 2) ? h16 : agg16) + (size_t)ns * D + (q & 1) * 64;
            #pragma unroll
            for (int i = 0; i < 8; ++i)
                *(uint4*)(dst + i * 8) = *(const uint4*)(src + i * 8);
        } else {
            const float4* src = (const float4*)(((q < 2) ? h : aggf) + (size_t)ns * D + (q & 1) * 64);
            #pragma unroll
            for (int i = 0; i < 8; ++i) {
                float4 a = src[2 * i], b = src[2 * i + 1];
                u32 p0 = (u32)f2bf(a.x) | ((u32)f2bf(a.y) << 16);
                u32 p1 = (u32)f2bf(a.z) | ((u32)f2bf(a.w) << 16);
                u32 p2 = (u32)f2bf(b.x) | ((u32)f2bf(b.y) << 16);
                u32 p3 = (u32)f2bf(b.z) | ((u32)f2bf(b.w) << 16);
                *(uint4*)(dst + i * 8) = make_uint4(p0, p1, p2, p3);
            }
        }
    }
    __syncthreads();

    const int lrow = lane & 15;
    const int kg = lane >> 4;
    const int g4 = kg * 4;
    const int nbase = wid * 32;

    f32x4 acc[4][2] = {};
    {
        bf16x8 B1[16];
        #pragma unroll
        for (int nn = 0; nn < 2; ++nn)
            #pragma unroll
            for (int s = 0; s < 8; ++s)
                B1[nn * 8 + s] = *(const bf16x8*)(wt + 49152 + (size_t)(nbase + nn * 16 + lrow) * 256 + s * 32 + kg * 8);

        #pragma unroll
        for (int s = 0; s < 8; ++s) {
            bf16x8 a[4];
            #pragma unroll
            for (int m = 0; m < 4; ++m)
                a[m] = *(const bf16x8*)(sX + (m * 16 + lrow) * SXS + s * 32 + kg * 8);
            #pragma unroll
            for (int m = 0; m < 4; ++m)
                #pragma unroll
                for (int nn = 0; nn < 2; ++nn)
                    acc[m][nn] = __builtin_amdgcn_mfma_f32_16x16x32_bf16(a[m], B1[nn * 8 + s], acc[m][nn], 0, 0, 0);
        }
    }

    #pragma unroll
    for (int nn = 0; nn < 2; ++nn) {
        int out = nbase + nn * 16 + lrow;
        float bb = bn1[out];
        #pragma unroll
        for (int m = 0; m < 4; ++m)
            #pragma unroll
            for (int r = 0; r < 4; ++r)
                sH1[(m * 16 + g4 + r) * SHS + out] = f2bf(silu_f(acc[m][nn][r] + bb));
    }
    __syncthreads();

    f32x4 acc2[4][2] = {};
    {
        bf16x8 B2[8];
        #pragma unroll
        for (int nn = 0; nn < 2; ++nn)
            #pragma unroll
            for (int s = 0; s < 4; ++s)
                B2[nn * 4 + s] = *(const bf16x8*)(wt + 81920 + (size_t)(nbase + nn * 16 + lrow) * 128 + s * 32 + kg * 8);

        #pragma unroll
        for (int s = 0; s < 4; ++s) {
            bf16x8 a[4];
            #pragma unroll
            for (int m = 0; m < 4; ++m)
                a[m] = *(const bf16x8*)(sH1 + (m * 16 + lrow) * SHS + s * 32 + kg * 8);
            #pragma unroll
            for (int m = 0; m < 4; ++m)
                #pragma unroll
                for (int nn = 0; nn < 2; ++nn)
                    acc2[m][nn] = __builtin_amdgcn_mfma_f32_16x16x32_bf16(a[m], B2[nn * 4 + s], acc2[m][nn], 0, 0, 0);
        }
    }
    __syncthreads();

    float* sXf = (float*)sX;
    #pragma unroll
    for (int nn = 0; nn < 2; ++nn) {
        int out = nbase + nn * 16 + lrow;
        float bb = bn2[out];
        #pragma unroll
        for (int m = 0; m < 4; ++m)
            #pragma unroll
            for (int r = 0; r < 4; ++r)
                sXf[(m * 16 + g4 + r) * 132 + out] = acc2[m][nn][r] + bb;
    }
    __syncthreads();

    {
        const int f4 = t & 31;
        const int nb = t >> 5;
        #pragma unroll
        for (int i = 0; i < 8; ++i) {
            int nl = nb + i * 8;
            int ng = n0 + nl;
            if (ng < N) {
                f32x4 v = *(const f32x4*)&sXf[nl * 132 + f4 * 4];
                const f32x4 hv = *(const f32x4*)&h[(size_t)ng * D + f4 * 4];
                v += hv;
                *(f32x4*)&h_out[(size_t)ng * D + f4 * 4] = v;
            }
        }
    }
}

extern "C" void kernel_launch(void* const* d_in, const int* in_sizes, int n_in,
                              void* d_out, int out_size, void* d_ws, size_t ws_size,
                              hipStream_t stream) {
    const float* h     = (const float*)d_in[0];
    const int*   ei    = (const int*)d_in[1];
    const float* coord = (const float*)d_in[2];
    const float* lbox  = (const float*)d_in[4];
    const float* We1   = (const float*)d_in[5];
    const float* be1   = (const float*)d_in[6];
    const float* We2   = (const float*)d_in[7];
    const float* be2   = (const float*)d_in[8];
    const float* Wn1   = (const float*)d_in[9];
    const float* bn1   = (const float*)d_in[10];
    const float* Wn2   = (const float*)d_in[11];
    const float* bn2   = (const float*)d_in[12];

    const int N = in_sizes[0] / D;
    const int E = in_sizes[1] / 2;

    float* out       = (float*)d_out;
    float* h_out     = out;                       // [N,128]
    float* coord_out = out + (size_t)N * D;       // [N,3]
    float* ef_out    = coord_out + (size_t)N * 3; // [E,128]

    // workspace layout
    int* wsi = (int*)d_ws;
    u16* wt     = (u16*)d_ws;                     // 98304 u16 = 49152 ints
    int* offs   = wsi + 49152;                    // N+1 (padded N+8)
    int* cursor = offs + (N + 8);                 // N   (padded N+8)
    int* bsum   = cursor + (N + 8);               // 64
    int* perm   = bsum + 64;                      // E
    u16* h16    = (u16*)(perm + E);               // N*128 bf16
    u16* agg16  = h16 + (size_t)N * D;            // N*128 bf16

    size_t need16 = (size_t)((char*)(agg16 + (size_t)N * D) - (char*)d_ws);
    const bool use16 = ws_size >= need16;
    const u16* h16p = use16 ? h16 : nullptr;
    const u16* agg16p = use16 ? agg16 : nullptr;
    float* aggf = h_out;                          // fallback f32 agg region

    const int nb1 = (N + 1 + 1023) / 1024;        // scan1 blocks (<=64)

    prep_weights<<<384, 256, 0, stream>>>(We1, We2, Wn1, Wn2, wt);
    if (use16) prep_h16<<<((N * D / 8) + 255) / 256, 256, 0, stream>>>(h, h16, N * D / 8);
    coord_kernel<<<(N * 3 + 255) / 256, 256, 0, stream>>>(coord, lbox, coord_out, N * 3);

    // CSR build
    hipMemsetAsync(cursor, 0, (size_t)N * sizeof(int), stream);
    hist_kernel<<<(E + 255) / 256, 256, 0, stream>>>(ei, cursor, E);
    scan1_kernel<<<nb1, 256, 0, stream>>>(cursor, offs, bsum, N + 1);
    scan2_kernel<<<1, 64, 0, stream>>>(bsum, nb1);
    scan3_kernel<<<(N + 1 + 255) / 256, 256, 0, stream>>>(offs, bsum, cursor, N + 1);
    scatter_kernel<<<(E + 255) / 256, 256, 0, stream>>>(ei, cursor, perm, E);

    edge_kernel<<<(E + 63) / 64, 256, 0, stream>>>(
        h, h16p, ei, coord, lbox, wt, We1, be1, be2, ef_out, E);

    agg_kernel<<<(N + 3) / 4, 256, 0, stream>>>(ef_out, offs, perm,
        use16 ? agg16 : nullptr, aggf, N);

    node_kernel<<<(N + 63) / 64, 256, 0, stream>>>(
        h, h16p, aggf, agg16p, wt, bn1, bn2, h_out, N);
}

// Round 5
// 346.476 us; speedup vs baseline: 4.3993x; 1.2035x over previous
//
#include <hip/hip_runtime.h>
#include <math.h>

#define D 128
#define SXS 264   // sX stride in bf16 elems
#define SHS 136   // sH1 stride

typedef unsigned int u32;
typedef unsigned short u16;
typedef __attribute__((ext_vector_type(8))) short bf16x8;
typedef __attribute__((ext_vector_type(4))) float f32x4;

__device__ __forceinline__ u16 f2bf(float f) {
    u32 u = __float_as_uint(f);
    return (u16)((u + 0x7FFFu + ((u >> 16) & 1u)) >> 16); // RNE
}
__device__ __forceinline__ float silu_f(float x) { return x / (1.0f + __expf(-x)); }

// ---------------- coord: out = remainder(coord, l) ----------------
__global__ void coord_kernel(const float* __restrict__ coord,
                             const float* __restrict__ lbox,
                             float* __restrict__ out, int n3) {
    int i = blockIdx.x * 256 + threadIdx.x;
    if (i < n3) {
        float ld = lbox[i % 3];
        float c = coord[i];
        float r = fmodf(c, ld);
        if (r < 0.f) r += ld;
        out[i] = r;
    }
}

// ---------------- weight prep: bf16 transposed Wt[n][k] into ws ----------------
__global__ void prep_weights(const float* __restrict__ We1, const float* __restrict__ We2,
                             const float* __restrict__ Wn1, const float* __restrict__ Wn2,
                             u16* __restrict__ wt) {
    int i = blockIdx.x * 256 + threadIdx.x;
    if (i < 32768)        { int n = i >> 8, k = i & 255;              wt[i] = f2bf(We1[(size_t)k*D + n]); }
    else if (i < 49152)   { int j = i - 32768; int n = j >> 7, k = j & 127; wt[i] = f2bf(We2[(size_t)k*D + n]); }
    else if (i < 81920)   { int j = i - 49152; int n = j >> 8, k = j & 255; wt[i] = f2bf(Wn1[(size_t)k*D + n]); }
    else if (i < 98304)   { int j = i - 81920; int n = j >> 7, k = j & 127; wt[i] = f2bf(Wn2[(size_t)k*D + n]); }
}

// ---------------- h -> bf16 copy ----------------
__global__ void prep_h16(const float* __restrict__ h, u16* __restrict__ h16, int total8) {
    int i = blockIdx.x * 256 + threadIdx.x;
    if (i < total8) {
        const float4* s = (const float4*)(h + (size_t)i * 8);
        float4 a = s[0], b = s[1];
        u32 p0 = (u32)f2bf(a.x) | ((u32)f2bf(a.y) << 16);
        u32 p1 = (u32)f2bf(a.z) | ((u32)f2bf(a.w) << 16);
        u32 p2 = (u32)f2bf(b.x) | ((u32)f2bf(b.y) << 16);
        u32 p3 = (u32)f2bf(b.z) | ((u32)f2bf(b.w) << 16);
        *(uint4*)(h16 + (size_t)i * 8) = make_uint4(p0, p1, p2, p3);
    }
}

// ---------------- CSR build ----------------
__global__ void hist_kernel(const int* __restrict__ ei, int* __restrict__ cnt, int E) {
    int e = blockIdx.x * 256 + threadIdx.x;
    if (e < E) atomicAdd(&cnt[ei[e]], 1);
}

__global__ void scan1_kernel(const int* __restrict__ cnt, int* __restrict__ offs,
                             int* __restrict__ bsum, int n /* = N+1 */) {
    __shared__ int s[256];
    int t = threadIdx.x, b = blockIdx.x;
    int base = b * 1024 + t * 4;
    int v[4];
    #pragma unroll
    for (int i = 0; i < 4; ++i) { int idx = base + i; v[i] = (idx < n - 1) ? cnt[idx] : 0; }
    int lsum = v[0] + v[1] + v[2] + v[3];
    s[t] = lsum; __syncthreads();
    #pragma unroll
    for (int off = 1; off < 256; off <<= 1) {
        int x = (t >= off) ? s[t - off] : 0; __syncthreads();
        s[t] += x; __syncthreads();
    }
    int run = s[t] - lsum;
    #pragma unroll
    for (int i = 0; i < 4; ++i) { int idx = base + i; if (idx < n) offs[idx] = run; run += v[i]; }
    if (t == 255) bsum[b] = s[255];
}

__global__ void scan2_kernel(int* __restrict__ bsum, int nb) {
    __shared__ int s[64];
    int t = threadIdx.x;
    int orig = (t < nb) ? bsum[t] : 0;
    s[t] = orig; __syncthreads();
    #pragma unroll
    for (int off = 1; off < 64; off <<= 1) {
        int x = (t >= off) ? s[t - off] : 0; __syncthreads();
        s[t] += x; __syncthreads();
    }
    if (t < nb) bsum[t] = s[t] - orig;
}

__global__ void scan3_kernel(int* __restrict__ offs, const int* __restrict__ bsum,
                             int* __restrict__ cursor, int n) {
    int i = blockIdx.x * 256 + threadIdx.x;
    if (i < n) {
        int v = offs[i] + bsum[i >> 10];
        offs[i] = v;
        if (i < n - 1) cursor[i] = v;
    }
}

__global__ void scatter_kernel(const int* __restrict__ ei, int* __restrict__ cursor,
                               int* __restrict__ perm, int E) {
    int e = blockIdx.x * 256 + threadIdx.x;
    if (e < E) { int p = atomicAdd(&cursor[ei[e]], 1); perm[p] = e; }
}

// ---------------- edge model (MFMA; sorted edges; fused scatter-reduce) ----------------
__global__ __launch_bounds__(256, 3) void edge_kernel(
    const float* __restrict__ h, const u16* __restrict__ h16,
    const int* __restrict__ ei, const int* __restrict__ perm,
    const float* __restrict__ coord, const float* __restrict__ lbox,
    const u16* __restrict__ wt,
    const float* __restrict__ We1, const float* __restrict__ be1,
    const float* __restrict__ be2,
    float* __restrict__ ef_out, float* __restrict__ aggf, int E)
{
    __shared__ __align__(16) u16 sX[64 * SXS];
    __shared__ __align__(16) u16 sH1[64 * SHS];
    __shared__ int srow[64], scol[64], sEid[64];
    __shared__ float sRad[64];

    const int t = threadIdx.x;
    const int lane = t & 63;
    const int wid = t >> 6;
    const int p0 = blockIdx.x * 64;

    if (t < 64) {
        int slot = p0 + t;
        int eg = perm[(slot < E) ? slot : (E - 1)];
        sEid[t] = (p0 + t < E) ? eg : -1;
        srow[t] = ei[eg];
        scol[t] = ei[(size_t)E + eg];
    }
    __syncthreads();

    // stage X = [h[row] | h[col]] as bf16, plus radial
    {
        const int e = t & 63;
        const int q = t >> 6;
        const int r = srow[e], c = scol[e];
        u16* dst = sX + e * SXS + q * 64;
        if (h16) {
            const u16* src = h16 + (size_t)((q < 2) ? r : c) * D + (q & 1) * 64;
            #pragma unroll
            for (int i = 0; i < 8; ++i)
                *(uint4*)(dst + i * 8) = *(const uint4*)(src + i * 8);
        } else {
            const float4* src = (const float4*)((q < 2) ? (h + (size_t)r * D + (q & 1) * 64)
                                                        : (h + (size_t)c * D + (q & 1) * 64));
            #pragma unroll
            for (int i = 0; i < 8; ++i) {
                float4 a = src[2 * i], b = src[2 * i + 1];
                u32 q0 = (u32)f2bf(a.x) | ((u32)f2bf(a.y) << 16);
                u32 q1 = (u32)f2bf(a.z) | ((u32)f2bf(a.w) << 16);
                u32 q2 = (u32)f2bf(b.x) | ((u32)f2bf(b.y) << 16);
                u32 q3 = (u32)f2bf(b.z) | ((u32)f2bf(b.w) << 16);
                *(uint4*)(dst + i * 8) = make_uint4(q0, q1, q2, q3);
            }
        }
        if (t < 64) {
            int rr = srow[t], cc = scol[t];
            float rad = 0.f;
            #pragma unroll
            for (int d3 = 0; d3 < 3; ++d3) {
                float df = coord[(size_t)rr * 3 + d3] - coord[(size_t)cc * 3 + d3];
                float ld = lbox[d3];
                df = (df >  0.5f * ld) ? df - ld : df;
                df = (df < -0.5f * ld) ? df + ld : df;
                rad += df * df;
            }
            sRad[t] = rad;
        }
    }
    __syncthreads();

    const int lrow = lane & 15;
    const int kg = lane >> 4;
    const int g4 = kg * 4;
    const int nbase = wid * 32;

    // ---- GEMM1: all 64 edges x out-slice [nbase, nbase+32), K=256 ----
    f32x4 acc[4][2] = {};
    {
        bf16x8 B1[16];
        #pragma unroll
        for (int nn = 0; nn < 2; ++nn)
            #pragma unroll
            for (int s = 0; s < 8; ++s)
                B1[nn * 8 + s] = *(const bf16x8*)(wt + (size_t)(nbase + nn * 16 + lrow) * 256 + s * 32 + kg * 8);

        #pragma unroll
        for (int s = 0; s < 8; ++s) {
            bf16x8 a[4];
            #pragma unroll
            for (int m = 0; m < 4; ++m)
                a[m] = *(const bf16x8*)(sX + (m * 16 + lrow) * SXS + s * 32 + kg * 8);
            #pragma unroll
            for (int m = 0; m < 4; ++m)
                #pragma unroll
                for (int nn = 0; nn < 2; ++nn)
                    acc[m][nn] = __builtin_amdgcn_mfma_f32_16x16x32_bf16(a[m], B1[nn * 8 + s], acc[m][nn], 0, 0, 0);
        }
    }

    // rank-1 radial + bias + SiLU -> sH1 (bf16)
    #pragma unroll
    for (int nn = 0; nn < 2; ++nn) {
        int out = nbase + nn * 16 + lrow;
        float wl = We1[(size_t)256 * D + out];
        float bb = be1[out];
        #pragma unroll
        for (int m = 0; m < 4; ++m) {
            #pragma unroll
            for (int r = 0; r < 4; ++r) {
                int e = m * 16 + g4 + r;
                float v = acc[m][nn][r] + sRad[e] * wl + bb;
                sH1[e * SHS + out] = f2bf(silu_f(v));
            }
        }
    }
    __syncthreads();

    // ---- GEMM2: K=128 ----
    f32x4 acc2[4][2] = {};
    {
        bf16x8 B2[8];
        #pragma unroll
        for (int nn = 0; nn < 2; ++nn)
            #pragma unroll
            for (int s = 0; s < 4; ++s)
                B2[nn * 4 + s] = *(const bf16x8*)(wt + 32768 + (size_t)(nbase + nn * 16 + lrow) * 128 + s * 32 + kg * 8);

        #pragma unroll
        for (int s = 0; s < 4; ++s) {
            bf16x8 a[4];
            #pragma unroll
            for (int m = 0; m < 4; ++m)
                a[m] = *(const bf16x8*)(sH1 + (m * 16 + lrow) * SHS + s * 32 + kg * 8);
            #pragma unroll
            for (int m = 0; m < 4; ++m)
                #pragma unroll
                for (int nn = 0; nn < 2; ++nn)
                    acc2[m][nn] = __builtin_amdgcn_mfma_f32_16x16x32_bf16(a[m], B2[nn * 4 + s], acc2[m][nn], 0, 0, 0);
        }
    }
    __syncthreads();   // all waves done reading sX/sH1 before sXf overwrite

    // bias + SiLU -> f32 transpose buffer (reuse sX)
    float* sXf = (float*)sX;   // stride 132 f32
    #pragma unroll
    for (int nn = 0; nn < 2; ++nn) {
        int out = nbase + nn * 16 + lrow;
        float bb = be2[out];
        #pragma unroll
        for (int m = 0; m < 4; ++m)
            #pragma unroll
            for (int r = 0; r < 4; ++r)
                sXf[(m * 16 + g4 + r) * 132 + out] = silu_f(acc2[m][nn][r] + bb);
    }
    __syncthreads();

    // coalesced scattered write-out (rows random but each row 512B contiguous)
    {
        const int f4 = t & 31;
        const int eb = t >> 5;
        #pragma unroll
        for (int i = 0; i < 8; ++i) {
            int e = eb + i * 8;
            int eg = sEid[e];
            if (eg >= 0)
                *(f32x4*)&ef_out[(size_t)eg * D + f4 * 4] = *(const f32x4*)&sXf[e * 132 + f4 * 4];
        }
    }

    // fused segmented reduce: thread owns column (t&127); half (t>>7) walks 32 sorted edges
    {
        const int ct = t & 127;
        const int half = t >> 7;
        const int ebeg = half * 32, eend = ebeg + 32;
        float run = 0.f;
        int prev = srow[ebeg];
        for (int e = ebeg; e < eend; ++e) {
            int r = srow[e];
            if (r != prev) {
                if (run != 0.f) atomicAdd(&aggf[(size_t)prev * D + ct], run);
                run = 0.f; prev = r;
            }
            if (sEid[e] >= 0) run += sXf[e * 132 + ct];
        }
        if (run != 0.f) atomicAdd(&aggf[(size_t)prev * D + ct], run);
    }
}

// ---------------- node model (MFMA; h16 + f32 agg in h_out region) ----------------
__global__ __launch_bounds__(256, 3) void node_kernel(
    const float* __restrict__ h, const u16* __restrict__ h16,
    const float* __restrict__ aggf,
    const u16* __restrict__ wt,
    const float* __restrict__ bn1, const float* __restrict__ bn2,
    float* __restrict__ h_out, int N)
{
    __shared__ __align__(16) u16 sX[64 * SXS];
    __shared__ __align__(16) u16 sH1[64 * SHS];

    const int t = threadIdx.x;
    const int lane = t & 63;
    const int wid = t >> 6;
    const int n0 = blockIdx.x * 64;

    {
        const int e = t & 63;
        const int q = t >> 6;
        int ng = n0 + e; int ns = (ng < N) ? ng : N - 1;
        u16* dst = sX + e * SXS + q * 64;
        if (q < 2 && h16) {
            const u16* src = h16 + (size_t)ns * D + (q & 1) * 64;
            #pragma unroll
            for (int i = 0; i < 8; ++i)
                *(uint4*)(dst + i * 8) = *(const uint4*)(src + i * 8);
        } else {
            const float4* src = (const float4*)(((q < 2) ? h : aggf) + (size_t)ns * D + (q & 1) * 64);
            #pragma unroll
            for (int i = 0; i < 8; ++i) {
                float4 a = src[2 * i], b = src[2 * i + 1];
                u32 q0 = (u32)f2bf(a.x) | ((u32)f2bf(a.y) << 16);
                u32 q1 = (u32)f2bf(a.z) | ((u32)f2bf(a.w) << 16);
                u32 q2 = (u32)f2bf(b.x) | ((u32)f2bf(b.y) << 16);
                u32 q3 = (u32)f2bf(b.z) | ((u32)f2bf(b.w) << 16);
                *(uint4*)(dst + i * 8) = make_uint4(q0, q1, q2, q3);
            }
        }
    }
    __syncthreads();

    const int lrow = lane & 15;
    const int kg = lane >> 4;
    const int g4 = kg * 4;
    const int nbase = wid * 32;

    f32x4 acc[4][2] = {};
    {
        bf16x8 B1[16];
        #pragma unroll
        for (int nn = 0; nn < 2; ++nn)
            #pragma unroll
            for (int s = 0; s < 8; ++s)
                B1[nn * 8 + s] = *(const bf16x8*)(wt + 49152 + (size_t)(nbase + nn * 16 + lrow) * 256 + s * 32 + kg * 8);

        #pragma unroll
        for (int s = 0; s < 8; ++s) {
            bf16x8 a[4];
            #pragma unroll
            for (int m = 0; m < 4; ++m)
                a[m] = *(const bf16x8*)(sX + (m * 16 + lrow) * SXS + s * 32 + kg * 8);
            #pragma unroll
            for (int m = 0; m < 4; ++m)
                #pragma unroll
                for (int nn = 0; nn < 2; ++nn)
                    acc[m][nn] = __builtin_amdgcn_mfma_f32_16x16x32_bf16(a[m], B1[nn * 8 + s], acc[m][nn], 0, 0, 0);
        }
    }

    #pragma unroll
    for (int nn = 0; nn < 2; ++nn) {
        int out = nbase + nn * 16 + lrow;
        float bb = bn1[out];
        #pragma unroll
        for (int m = 0; m < 4; ++m)
            #pragma unroll
            for (int r = 0; r < 4; ++r)
                sH1[(m * 16 + g4 + r) * SHS + out] = f2bf(silu_f(acc[m][nn][r] + bb));
    }
    __syncthreads();

    f32x4 acc2[4][2] = {};
    {
        bf16x8 B2[8];
        #pragma unroll
        for (int nn = 0; nn < 2; ++nn)
            #pragma unroll
            for (int s = 0; s < 4; ++s)
                B2[nn * 4 + s] = *(const bf16x8*)(wt + 81920 + (size_t)(nbase + nn * 16 + lrow) * 128 + s * 32 + kg * 8);

        #pragma unroll
        for (int s = 0; s < 4; ++s) {
            bf16x8 a[4];
            #pragma unroll
            for (int m = 0; m < 4; ++m)
                a[m] = *(const bf16x8*)(sH1 + (m * 16 + lrow) * SHS + s * 32 + kg * 8);
            #pragma unroll
            for (int m = 0; m < 4; ++m)
                #pragma unroll
                for (int nn = 0; nn < 2; ++nn)
                    acc2[m][nn] = __builtin_amdgcn_mfma_f32_16x16x32_bf16(a[m], B2[nn * 4 + s], acc2[m][nn], 0, 0, 0);
        }
    }
    __syncthreads();

    float* sXf = (float*)sX;
    #pragma unroll
    for (int nn = 0; nn < 2; ++nn) {
        int out = nbase + nn * 16 + lrow;
        float bb = bn2[out];
        #pragma unroll
        for (int m = 0; m < 4; ++m)
            #pragma unroll
            for (int r = 0; r < 4; ++r)
                sXf[(m * 16 + g4 + r) * 132 + out] = acc2[m][nn][r] + bb;
    }
    __syncthreads();

    {
        const int f4 = t & 31;
        const int nb = t >> 5;
        #pragma unroll
        for (int i = 0; i < 8; ++i) {
            int nl = nb + i * 8;
            int ng = n0 + nl;
            if (ng < N) {
                f32x4 v = *(const f32x4*)&sXf[nl * 132 + f4 * 4];
                const f32x4 hv = *(const f32x4*)&h[(size_t)ng * D + f4 * 4];
                v += hv;
                *(f32x4*)&h_out[(size_t)ng * D + f4 * 4] = v;
            }
        }
    }
}

extern "C" void kernel_launch(void* const* d_in, const int* in_sizes, int n_in,
                              void* d_out, int out_size, void* d_ws, size_t ws_size,
                              hipStream_t stream) {
    const float* h     = (const float*)d_in[0];
    const int*   ei    = (const int*)d_in[1];
    const float* coord = (const float*)d_in[2];
    const float* lbox  = (const float*)d_in[4];
    const float* We1   = (const float*)d_in[5];
    const float* be1   = (const float*)d_in[6];
    const float* We2   = (const float*)d_in[7];
    const float* be2   = (const float*)d_in[8];
    const float* Wn1   = (const float*)d_in[9];
    const float* bn1   = (const float*)d_in[10];
    const float* Wn2   = (const float*)d_in[11];
    const float* bn2   = (const float*)d_in[12];

    const int N = in_sizes[0] / D;
    const int E = in_sizes[1] / 2;

    float* out       = (float*)d_out;
    float* h_out     = out;                       // [N,128]
    float* coord_out = out + (size_t)N * D;       // [N,3]
    float* ef_out    = coord_out + (size_t)N * 3; // [E,128]
    float* aggf      = h_out;                     // f32 agg accumulator in-place

    // workspace layout
    int* wsi = (int*)d_ws;
    u16* wt     = (u16*)d_ws;                     // 98304 u16 = 49152 ints
    int* offs   = wsi + 49152;                    // N+1 (padded N+8)
    int* cursor = offs + (N + 8);                 // N   (padded N+8)
    int* bsum   = cursor + (N + 8);               // 64
    int* perm   = bsum + 64;                      // E
    u16* h16    = (u16*)(perm + E);               // N*128 bf16

    size_t need16 = (size_t)((char*)(h16 + (size_t)N * D) - (char*)d_ws);
    const bool use16 = ws_size >= need16;
    const u16* h16p = use16 ? h16 : nullptr;

    const int nb1 = (N + 1 + 1023) / 1024;        // scan1 blocks (<=64)

    prep_weights<<<384, 256, 0, stream>>>(We1, We2, Wn1, Wn2, wt);
    if (use16) prep_h16<<<((N * D / 8) + 255) / 256, 256, 0, stream>>>(h, h16, N * D / 8);
    coord_kernel<<<(N * 3 + 255) / 256, 256, 0, stream>>>(coord, lbox, coord_out, N * 3);

    // zero agg accumulator (h_out region)
    hipMemsetAsync(aggf, 0, (size_t)N * D * sizeof(float), stream);

    // CSR build
    hipMemsetAsync(cursor, 0, (size_t)N * sizeof(int), stream);
    hist_kernel<<<(E + 255) / 256, 256, 0, stream>>>(ei, cursor, E);
    scan1_kernel<<<nb1, 256, 0, stream>>>(cursor, offs, bsum, N + 1);
    scan2_kernel<<<1, 64, 0, stream>>>(bsum, nb1);
    scan3_kernel<<<(N + 1 + 255) / 256, 256, 0, stream>>>(offs, bsum, cursor, N + 1);
    scatter_kernel<<<(E + 255) / 256, 256, 0, stream>>>(ei, cursor, perm, E);

    edge_kernel<<<(E + 63) / 64, 256, 0, stream>>>(
        h, h16p, ei, perm, coord, lbox, wt, We1, be1, be2, ef_out, aggf, E);

    node_kernel<<<(N + 63) / 64, 256, 0, stream>>>(
        h, h16p, aggf, wt, bn1, bn2, h_out, N);
}

// Round 6
// 330.908 us; speedup vs baseline: 4.6063x; 1.0470x over previous
//
#include <hip/hip_runtime.h>
#include <math.h>

#define D 128
#define SXS 264   // sX stride in bf16 elems
#define SHS 136   // sH1 stride

typedef unsigned int u32;
typedef unsigned short u16;
typedef __attribute__((ext_vector_type(8))) short bf16x8;
typedef __attribute__((ext_vector_type(4))) float f32x4;

__device__ __forceinline__ u16 f2bf(float f) {
    u32 u = __float_as_uint(f);
    return (u16)((u + 0x7FFFu + ((u >> 16) & 1u)) >> 16); // RNE
}
__device__ __forceinline__ float silu_f(float x) { return x / (1.0f + __expf(-x)); }

// ---------------- coord: out = remainder(coord, l) ----------------
__global__ void coord_kernel(const float* __restrict__ coord,
                             const float* __restrict__ lbox,
                             float* __restrict__ out, int n3) {
    int i = blockIdx.x * 256 + threadIdx.x;
    if (i < n3) {
        float ld = lbox[i % 3];
        float c = coord[i];
        float r = fmodf(c, ld);
        if (r < 0.f) r += ld;
        out[i] = r;
    }
}

// ---------------- weight prep: bf16 transposed Wt[n][k] into ws ----------------
__global__ void prep_weights(const float* __restrict__ We1, const float* __restrict__ We2,
                             const float* __restrict__ Wn1, const float* __restrict__ Wn2,
                             u16* __restrict__ wt) {
    int i = blockIdx.x * 256 + threadIdx.x;
    if (i < 32768)        { int n = i >> 8, k = i & 255;              wt[i] = f2bf(We1[(size_t)k*D + n]); }
    else if (i < 49152)   { int j = i - 32768; int n = j >> 7, k = j & 127; wt[i] = f2bf(We2[(size_t)k*D + n]); }
    else if (i < 81920)   { int j = i - 49152; int n = j >> 8, k = j & 255; wt[i] = f2bf(Wn1[(size_t)k*D + n]); }
    else if (i < 98304)   { int j = i - 81920; int n = j >> 7, k = j & 127; wt[i] = f2bf(Wn2[(size_t)k*D + n]); }
}

// ---------------- h -> bf16 copy ----------------
__global__ void prep_h16(const float* __restrict__ h, u16* __restrict__ h16, int total8) {
    int i = blockIdx.x * 256 + threadIdx.x;
    if (i < total8) {
        const float4* s = (const float4*)(h + (size_t)i * 8);
        float4 a = s[0], b = s[1];
        u32 p0 = (u32)f2bf(a.x) | ((u32)f2bf(a.y) << 16);
        u32 p1 = (u32)f2bf(a.z) | ((u32)f2bf(a.w) << 16);
        u32 p2 = (u32)f2bf(b.x) | ((u32)f2bf(b.y) << 16);
        u32 p3 = (u32)f2bf(b.z) | ((u32)f2bf(b.w) << 16);
        *(uint4*)(h16 + (size_t)i * 8) = make_uint4(p0, p1, p2, p3);
    }
}

// ---------------- CSR build ----------------
__global__ void hist_kernel(const int* __restrict__ ei, int* __restrict__ cnt, int E) {
    int e = blockIdx.x * 256 + threadIdx.x;
    if (e < E) atomicAdd(&cnt[ei[e]], 1);
}

__global__ void scan1_kernel(const int* __restrict__ cnt, int* __restrict__ offs,
                             int* __restrict__ bsum, int n /* = N+1 */) {
    __shared__ int s[256];
    int t = threadIdx.x, b = blockIdx.x;
    int base = b * 1024 + t * 4;
    int v[4];
    #pragma unroll
    for (int i = 0; i < 4; ++i) { int idx = base + i; v[i] = (idx < n - 1) ? cnt[idx] : 0; }
    int lsum = v[0] + v[1] + v[2] + v[3];
    s[t] = lsum; __syncthreads();
    #pragma unroll
    for (int off = 1; off < 256; off <<= 1) {
        int x = (t >= off) ? s[t - off] : 0; __syncthreads();
        s[t] += x; __syncthreads();
    }
    int run = s[t] - lsum;
    #pragma unroll
    for (int i = 0; i < 4; ++i) { int idx = base + i; if (idx < n) offs[idx] = run; run += v[i]; }
    if (t == 255) bsum[b] = s[255];
}

__global__ void scan2_kernel(int* __restrict__ bsum, int nb) {
    __shared__ int s[64];
    int t = threadIdx.x;
    int orig = (t < nb) ? bsum[t] : 0;
    s[t] = orig; __syncthreads();
    #pragma unroll
    for (int off = 1; off < 64; off <<= 1) {
        int x = (t >= off) ? s[t - off] : 0; __syncthreads();
        s[t] += x; __syncthreads();
    }
    if (t < nb) bsum[t] = s[t] - orig;
}

__global__ void scan3_kernel(int* __restrict__ offs, const int* __restrict__ bsum,
                             int* __restrict__ cursor, int n) {
    int i = blockIdx.x * 256 + threadIdx.x;
    if (i < n) {
        int v = offs[i] + bsum[i >> 10];
        offs[i] = v;
        if (i < n - 1) cursor[i] = v;
    }
}

__global__ void scatter_kernel(const int* __restrict__ ei, int* __restrict__ cursor,
                               int* __restrict__ perm, int E) {
    int e = blockIdx.x * 256 + threadIdx.x;
    if (e < E) { int p = atomicAdd(&cursor[ei[e]], 1); perm[p] = e; }
}

// ---------------- edge model (MFMA; sorted edges; fused scatter-reduce) ----------------
__global__ __launch_bounds__(256, 3) void edge_kernel(
    const float* __restrict__ h, const u16* __restrict__ h16,
    const int* __restrict__ ei, const int* __restrict__ perm,
    const float* __restrict__ coord, const float* __restrict__ lbox,
    const u16* __restrict__ wt,
    const float* __restrict__ We1, const float* __restrict__ be1,
    const float* __restrict__ be2,
    float* __restrict__ ef_out, float* __restrict__ aggf, int E)
{
    __shared__ __align__(16) u16 sX[64 * SXS];
    __shared__ __align__(16) u16 sH1[64 * SHS];
    __shared__ int srow[64], scol[64], sEid[64];
    __shared__ float sRad[64];

    const int t = threadIdx.x;
    const int lane = t & 63;
    const int wid = t >> 6;

    // bijective XCD swizzle (m204): consecutive sorted-edge tiles -> same XCD L2
    int p0;
    {
        const int nwg = gridDim.x;
        const int orig = blockIdx.x;
        const int q = nwg >> 3, r = nwg & 7;
        const int xcd = orig & 7, idx = orig >> 3;
        const int tile = (xcd < r ? xcd * (q + 1) : r * (q + 1) + (xcd - r) * q) + idx;
        p0 = tile * 64;
    }

    if (t < 64) {
        int slot = p0 + t;
        int eg = perm[(slot < E) ? slot : (E - 1)];
        sEid[t] = (p0 + t < E) ? eg : -1;
        srow[t] = ei[eg];
        scol[t] = ei[(size_t)E + eg];
    }
    __syncthreads();

    // stage X = [h[row] | h[col]] as bf16, plus radial
    {
        const int e = t & 63;
        const int q = t >> 6;
        const int r = srow[e], c = scol[e];
        u16* dst = sX + e * SXS + q * 64;
        if (h16) {
            const u16* src = h16 + (size_t)((q < 2) ? r : c) * D + (q & 1) * 64;
            #pragma unroll
            for (int i = 0; i < 8; ++i)
                *(uint4*)(dst + i * 8) = *(const uint4*)(src + i * 8);
        } else {
            const float4* src = (const float4*)((q < 2) ? (h + (size_t)r * D + (q & 1) * 64)
                                                        : (h + (size_t)c * D + (q & 1) * 64));
            #pragma unroll
            for (int i = 0; i < 8; ++i) {
                float4 a = src[2 * i], b = src[2 * i + 1];
                u32 q0 = (u32)f2bf(a.x) | ((u32)f2bf(a.y) << 16);
                u32 q1 = (u32)f2bf(a.z) | ((u32)f2bf(a.w) << 16);
                u32 q2 = (u32)f2bf(b.x) | ((u32)f2bf(b.y) << 16);
                u32 q3 = (u32)f2bf(b.z) | ((u32)f2bf(b.w) << 16);
                *(uint4*)(dst + i * 8) = make_uint4(q0, q1, q2, q3);
            }
        }
        if (t < 64) {
            int rr = srow[t], cc = scol[t];
            float rad = 0.f;
            #pragma unroll
            for (int d3 = 0; d3 < 3; ++d3) {
                float df = coord[(size_t)rr * 3 + d3] - coord[(size_t)cc * 3 + d3];
                float ld = lbox[d3];
                df = (df >  0.5f * ld) ? df - ld : df;
                df = (df < -0.5f * ld) ? df + ld : df;
                rad += df * df;
            }
            sRad[t] = rad;
        }
    }
    __syncthreads();

    const int lrow = lane & 15;
    const int kg = lane >> 4;
    const int g4 = kg * 4;
    const int nbase = wid * 32;

    // ---- GEMM1: all 64 edges x out-slice [nbase, nbase+32), K=256 ----
    f32x4 acc[4][2] = {};
    {
        bf16x8 B1[16];
        #pragma unroll
        for (int nn = 0; nn < 2; ++nn)
            #pragma unroll
            for (int s = 0; s < 8; ++s)
                B1[nn * 8 + s] = *(const bf16x8*)(wt + (size_t)(nbase + nn * 16 + lrow) * 256 + s * 32 + kg * 8);

        #pragma unroll
        for (int s = 0; s < 8; ++s) {
            bf16x8 a[4];
            #pragma unroll
            for (int m = 0; m < 4; ++m)
                a[m] = *(const bf16x8*)(sX + (m * 16 + lrow) * SXS + s * 32 + kg * 8);
            #pragma unroll
            for (int m = 0; m < 4; ++m)
                #pragma unroll
                for (int nn = 0; nn < 2; ++nn)
                    acc[m][nn] = __builtin_amdgcn_mfma_f32_16x16x32_bf16(a[m], B1[nn * 8 + s], acc[m][nn], 0, 0, 0);
        }
    }

    // rank-1 radial + bias + SiLU -> sH1 (bf16)
    #pragma unroll
    for (int nn = 0; nn < 2; ++nn) {
        int out = nbase + nn * 16 + lrow;
        float wl = We1[(size_t)256 * D + out];
        float bb = be1[out];
        #pragma unroll
        for (int m = 0; m < 4; ++m) {
            #pragma unroll
            for (int r = 0; r < 4; ++r) {
                int e = m * 16 + g4 + r;
                float v = acc[m][nn][r] + sRad[e] * wl + bb;
                sH1[e * SHS + out] = f2bf(silu_f(v));
            }
        }
    }
    __syncthreads();

    // ---- GEMM2: K=128 ----
    f32x4 acc2[4][2] = {};
    {
        bf16x8 B2[8];
        #pragma unroll
        for (int nn = 0; nn < 2; ++nn)
            #pragma unroll
            for (int s = 0; s < 4; ++s)
                B2[nn * 4 + s] = *(const bf16x8*)(wt + 32768 + (size_t)(nbase + nn * 16 + lrow) * 128 + s * 32 + kg * 8);

        #pragma unroll
        for (int s = 0; s < 4; ++s) {
            bf16x8 a[4];
            #pragma unroll
            for (int m = 0; m < 4; ++m)
                a[m] = *(const bf16x8*)(sH1 + (m * 16 + lrow) * SHS + s * 32 + kg * 8);
            #pragma unroll
            for (int m = 0; m < 4; ++m)
                #pragma unroll
                for (int nn = 0; nn < 2; ++nn)
                    acc2[m][nn] = __builtin_amdgcn_mfma_f32_16x16x32_bf16(a[m], B2[nn * 4 + s], acc2[m][nn], 0, 0, 0);
        }
    }
    __syncthreads();   // all waves done reading sX/sH1 before sXf overwrite

    // bias + SiLU -> f32 transpose buffer (reuse sX)
    float* sXf = (float*)sX;   // stride 132 f32
    #pragma unroll
    for (int nn = 0; nn < 2; ++nn) {
        int out = nbase + nn * 16 + lrow;
        float bb = be2[out];
        #pragma unroll
        for (int m = 0; m < 4; ++m)
            #pragma unroll
            for (int r = 0; r < 4; ++r)
                sXf[(m * 16 + g4 + r) * 132 + out] = silu_f(acc2[m][nn][r] + bb);
    }
    __syncthreads();

    // non-temporal scattered write-out (keep ef stream out of L2/L3)
    {
        const int f4 = t & 31;
        const int eb = t >> 5;
        #pragma unroll
        for (int i = 0; i < 8; ++i) {
            int e = eb + i * 8;
            int eg = sEid[e];
            if (eg >= 0) {
                f32x4 v = *(const f32x4*)&sXf[e * 132 + f4 * 4];
                __builtin_nontemporal_store(v, (f32x4*)&ef_out[(size_t)eg * D + f4 * 4]);
            }
        }
    }

    // fused segmented reduce: thread owns column (t&127); half (t>>7) walks 32 sorted edges
    {
        const int ct = t & 127;
        const int half = t >> 7;
        const int ebeg = half * 32, eend = ebeg + 32;
        float run = 0.f;
        int prev = srow[ebeg];
        for (int e = ebeg; e < eend; ++e) {
            int r = srow[e];
            if (r != prev) {
                if (run != 0.f) atomicAdd(&aggf[(size_t)prev * D + ct], run);
                run = 0.f; prev = r;
            }
            if (sEid[e] >= 0) run += sXf[e * 132 + ct];
        }
        if (run != 0.f) atomicAdd(&aggf[(size_t)prev * D + ct], run);
    }
}

// ---------------- node model (MFMA; h16 + f32 agg in h_out region) ----------------
__global__ __launch_bounds__(256, 3) void node_kernel(
    const float* __restrict__ h, const u16* __restrict__ h16,
    const float* __restrict__ aggf,
    const u16* __restrict__ wt,
    const float* __restrict__ bn1, const float* __restrict__ bn2,
    float* __restrict__ h_out, int N)
{
    __shared__ __align__(16) u16 sX[64 * SXS];
    __shared__ __align__(16) u16 sH1[64 * SHS];

    const int t = threadIdx.x;
    const int lane = t & 63;
    const int wid = t >> 6;
    const int n0 = blockIdx.x * 64;

    {
        const int e = t & 63;
        const int q = t >> 6;
        int ng = n0 + e; int ns = (ng < N) ? ng : N - 1;
        u16* dst = sX + e * SXS + q * 64;
        if (q < 2 && h16) {
            const u16* src = h16 + (size_t)ns * D + (q & 1) * 64;
            #pragma unroll
            for (int i = 0; i < 8; ++i)
                *(uint4*)(dst + i * 8) = *(const uint4*)(src + i * 8);
        } else {
            const float4* src = (const float4*)(((q < 2) ? h : aggf) + (size_t)ns * D + (q & 1) * 64);
            #pragma unroll
            for (int i = 0; i < 8; ++i) {
                float4 a = src[2 * i], b = src[2 * i + 1];
                u32 q0 = (u32)f2bf(a.x) | ((u32)f2bf(a.y) << 16);
                u32 q1 = (u32)f2bf(a.z) | ((u32)f2bf(a.w) << 16);
                u32 q2 = (u32)f2bf(b.x) | ((u32)f2bf(b.y) << 16);
                u32 q3 = (u32)f2bf(b.z) | ((u32)f2bf(b.w) << 16);
                *(uint4*)(dst + i * 8) = make_uint4(q0, q1, q2, q3);
            }
        }
    }
    __syncthreads();

    const int lrow = lane & 15;
    const int kg = lane >> 4;
    const int g4 = kg * 4;
    const int nbase = wid * 32;

    f32x4 acc[4][2] = {};
    {
        bf16x8 B1[16];
        #pragma unroll
        for (int nn = 0; nn < 2; ++nn)
            #pragma unroll
            for (int s = 0; s < 8; ++s)
                B1[nn * 8 + s] = *(const bf16x8*)(wt + 49152 + (size_t)(nbase + nn * 16 + lrow) * 256 + s * 32 + kg * 8);

        #pragma unroll
        for (int s = 0; s < 8; ++s) {
            bf16x8 a[4];
            #pragma unroll
            for (int m = 0; m < 4; ++m)
                a[m] = *(const bf16x8*)(sX + (m * 16 + lrow) * SXS + s * 32 + kg * 8);
            #pragma unroll
            for (int m = 0; m < 4; ++m)
                #pragma unroll
                for (int nn = 0; nn < 2; ++nn)
                    acc[m][nn] = __builtin_amdgcn_mfma_f32_16x16x32_bf16(a[m], B1[nn * 8 + s], acc[m][nn], 0, 0, 0);
        }
    }

    #pragma unroll
    for (int nn = 0; nn < 2; ++nn) {
        int out = nbase + nn * 16 + lrow;
        float bb = bn1[out];
        #pragma unroll
        for (int m = 0; m < 4; ++m)
            #pragma unroll
            for (int r = 0; r < 4; ++r)
                sH1[(m * 16 + g4 + r) * SHS + out] = f2bf(silu_f(acc[m][nn][r] + bb));
    }
    __syncthreads();

    f32x4 acc2[4][2] = {};
    {
        bf16x8 B2[8];
        #pragma unroll
        for (int nn = 0; nn < 2; ++nn)
            #pragma unroll
            for (int s = 0; s < 4; ++s)
                B2[nn * 4 + s] = *(const bf16x8*)(wt + 81920 + (size_t)(nbase + nn * 16 + lrow) * 128 + s * 32 + kg * 8);

        #pragma unroll
        for (int s = 0; s < 4; ++s) {
            bf16x8 a[4];
            #pragma unroll
            for (int m = 0; m < 4; ++m)
                a[m] = *(const bf16x8*)(sH1 + (m * 16 + lrow) * SHS + s * 32 + kg * 8);
            #pragma unroll
            for (int m = 0; m < 4; ++m)
                #pragma unroll
                for (int nn = 0; nn < 2; ++nn)
                    acc2[m][nn] = __builtin_amdgcn_mfma_f32_16x16x32_bf16(a[m], B2[nn * 4 + s], acc2[m][nn], 0, 0, 0);
        }
    }
    __syncthreads();

    float* sXf = (float*)sX;
    #pragma unroll
    for (int nn = 0; nn < 2; ++nn) {
        int out = nbase + nn * 16 + lrow;
        float bb = bn2[out];
        #pragma unroll
        for (int m = 0; m < 4; ++m)
            #pragma unroll
            for (int r = 0; r < 4; ++r)
                sXf[(m * 16 + g4 + r) * 132 + out] = acc2[m][nn][r] + bb;
    }
    __syncthreads();

    {
        const int f4 = t & 31;
        const int nb = t >> 5;
        #pragma unroll
        for (int i = 0; i < 8; ++i) {
            int nl = nb + i * 8;
            int ng = n0 + nl;
            if (ng < N) {
                f32x4 v = *(const f32x4*)&sXf[nl * 132 + f4 * 4];
                const f32x4 hv = *(const f32x4*)&h[(size_t)ng * D + f4 * 4];
                v += hv;
                __builtin_nontemporal_store(v, (f32x4*)&h_out[(size_t)ng * D + f4 * 4]);
            }
        }
    }
}

extern "C" void kernel_launch(void* const* d_in, const int* in_sizes, int n_in,
                              void* d_out, int out_size, void* d_ws, size_t ws_size,
                              hipStream_t stream) {
    const float* h     = (const float*)d_in[0];
    const int*   ei    = (const int*)d_in[1];
    const float* coord = (const float*)d_in[2];
    const float* lbox  = (const float*)d_in[4];
    const float* We1   = (const float*)d_in[5];
    const float* be1   = (const float*)d_in[6];
    const float* We2   = (const float*)d_in[7];
    const float* be2   = (const float*)d_in[8];
    const float* Wn1   = (const float*)d_in[9];
    const float* bn1   = (const float*)d_in[10];
    const float* Wn2   = (const float*)d_in[11];
    const float* bn2   = (const float*)d_in[12];

    const int N = in_sizes[0] / D;
    const int E = in_sizes[1] / 2;

    float* out       = (float*)d_out;
    float* h_out     = out;                       // [N,128]
    float* coord_out = out + (size_t)N * D;       // [N,3]
    float* ef_out    = coord_out + (size_t)N * 3; // [E,128]
    float* aggf      = h_out;                     // f32 agg accumulator in-place

    // workspace layout
    int* wsi = (int*)d_ws;
    u16* wt     = (u16*)d_ws;                     // 98304 u16 = 49152 ints
    int* offs   = wsi + 49152;                    // N+1 (padded N+8)
    int* cursor = offs + (N + 8);                 // N   (padded N+8)
    int* bsum   = cursor + (N + 8);               // 64
    int* perm   = bsum + 64;                      // E
    u16* h16    = (u16*)(perm + E);               // N*128 bf16

    size_t need16 = (size_t)((char*)(h16 + (size_t)N * D) - (char*)d_ws);
    const bool use16 = ws_size >= need16;
    const u16* h16p = use16 ? h16 : nullptr;

    const int nb1 = (N + 1 + 1023) / 1024;        // scan1 blocks (<=64)

    prep_weights<<<384, 256, 0, stream>>>(We1, We2, Wn1, Wn2, wt);
    if (use16) prep_h16<<<((N * D / 8) + 255) / 256, 256, 0, stream>>>(h, h16, N * D / 8);
    coord_kernel<<<(N * 3 + 255) / 256, 256, 0, stream>>>(coord, lbox, coord_out, N * 3);

    // zero agg accumulator (h_out region)
    hipMemsetAsync(aggf, 0, (size_t)N * D * sizeof(float), stream);

    // CSR build
    hipMemsetAsync(cursor, 0, (size_t)N * sizeof(int), stream);
    hist_kernel<<<(E + 255) / 256, 256, 0, stream>>>(ei, cursor, E);
    scan1_kernel<<<nb1, 256, 0, stream>>>(cursor, offs, bsum, N + 1);
    scan2_kernel<<<1, 64, 0, stream>>>(bsum, nb1);
    scan3_kernel<<<(N + 1 + 255) / 256, 256, 0, stream>>>(offs, bsum, cursor, N + 1);
    scatter_kernel<<<(E + 255) / 256, 256, 0, stream>>>(ei, cursor, perm, E);

    edge_kernel<<<(E + 63) / 64, 256, 0, stream>>>(
        h, h16p, ei, perm, coord, lbox, wt, We1, be1, be2, ef_out, aggf, E);

    node_kernel<<<(N + 63) / 64, 256, 0, stream>>>(
        h, h16p, aggf, wt, bn1, bn2, h_out, N);
}

// Round 7
// 310.469 us; speedup vs baseline: 4.9095x; 1.0658x over previous
//
#include <hip/hip_runtime.h>
#include <math.h>

#define D 128
#define SXS 264   // node sX stride (u16): 132 dwords
#define SHS 132   // layer-1 activation stride (u16): 66 dwords == 2 mod 8 -> conflict-free epi1
#define SFS 132   // f32 out-buffer stride (dwords)

typedef unsigned int u32;
typedef unsigned short u16;
typedef __attribute__((ext_vector_type(8))) short bf16x8;
typedef __attribute__((ext_vector_type(4))) float f32x4;

__device__ __forceinline__ float bfl(u32 u) { return __uint_as_float(u << 16); }
__device__ __forceinline__ float bfh(u32 u) { return __uint_as_float(u & 0xFFFF0000u); }
__device__ __forceinline__ u16 f2bf(float f) {
    u32 u = __float_as_uint(f);
    return (u16)((u + 0x7FFFu + ((u >> 16) & 1u)) >> 16); // RNE
}
__device__ __forceinline__ float silu_f(float x) { return x / (1.0f + __expf(-x)); }

// ---------------- coord: out = remainder(coord, l) ----------------
__global__ void coord_kernel(const float* __restrict__ coord,
                             const float* __restrict__ lbox,
                             float* __restrict__ out, int n3) {
    int i = blockIdx.x * 256 + threadIdx.x;
    if (i < n3) {
        float ld = lbox[i % 3];
        float c = coord[i];
        float r = fmodf(c, ld);
        if (r < 0.f) r += ld;
        out[i] = r;
    }
}

// ---------------- weight prep: bf16 transposed Wt[n][k] into ws ----------------
__global__ void prep_weights(const float* __restrict__ We1, const float* __restrict__ We2,
                             const float* __restrict__ Wn1, const float* __restrict__ Wn2,
                             u16* __restrict__ wt) {
    int i = blockIdx.x * 256 + threadIdx.x;
    if (i < 32768)        { int n = i >> 8, k = i & 255;              wt[i] = f2bf(We1[(size_t)k*D + n]); }
    else if (i < 49152)   { int j = i - 32768; int n = j >> 7, k = j & 127; wt[i] = f2bf(We2[(size_t)k*D + n]); }
    else if (i < 81920)   { int j = i - 49152; int n = j >> 8, k = j & 255; wt[i] = f2bf(Wn1[(size_t)k*D + n]); }
    else if (i < 98304)   { int j = i - 81920; int n = j >> 7, k = j & 127; wt[i] = f2bf(Wn2[(size_t)k*D + n]); }
}

// ---------------- CSR build ----------------
__global__ void hist_kernel(const int* __restrict__ ei, int* __restrict__ cnt, int E) {
    int e = blockIdx.x * 256 + threadIdx.x;
    if (e < E) atomicAdd(&cnt[ei[e]], 1);
}

__global__ void scan1_kernel(const int* __restrict__ cnt, int* __restrict__ offs,
                             int* __restrict__ bsum, int n /* = N+1 */) {
    __shared__ int s[256];
    int t = threadIdx.x, b = blockIdx.x;
    int base = b * 1024 + t * 4;
    int v[4];
    #pragma unroll
    for (int i = 0; i < 4; ++i) { int idx = base + i; v[i] = (idx < n - 1) ? cnt[idx] : 0; }
    int lsum = v[0] + v[1] + v[2] + v[3];
    s[t] = lsum; __syncthreads();
    #pragma unroll
    for (int off = 1; off < 256; off <<= 1) {
        int x = (t >= off) ? s[t - off] : 0; __syncthreads();
        s[t] += x; __syncthreads();
    }
    int run = s[t] - lsum;
    #pragma unroll
    for (int i = 0; i < 4; ++i) { int idx = base + i; if (idx < n) offs[idx] = run; run += v[i]; }
    if (t == 255) bsum[b] = s[255];
}

__global__ void scan2_kernel(int* __restrict__ bsum, int nb) {
    __shared__ int s[64];
    int t = threadIdx.x;
    int orig = (t < nb) ? bsum[t] : 0;
    s[t] = orig; __syncthreads();
    #pragma unroll
    for (int off = 1; off < 64; off <<= 1) {
        int x = (t >= off) ? s[t - off] : 0; __syncthreads();
        s[t] += x; __syncthreads();
    }
    if (t < nb) bsum[t] = s[t] - orig;
}

__global__ void scan3_kernel(int* __restrict__ offs, const int* __restrict__ bsum,
                             int* __restrict__ cursor, int n) {
    int i = blockIdx.x * 256 + threadIdx.x;
    if (i < n) {
        int v = offs[i] + bsum[i >> 10];
        offs[i] = v;
        if (i < n - 1) cursor[i] = v;
    }
}

__global__ void scatter_kernel(const int* __restrict__ ei, int* __restrict__ cursor,
                               int* __restrict__ perm, int E) {
    int e = blockIdx.x * 256 + threadIdx.x;
    if (e < E) { int p = atomicAdd(&cursor[ei[e]], 1); perm[p] = e; }
}

// ---------------- P/Q precompute: P = h@W_top + be1, Q = h@W_mid (bf16) ----------------
__global__ __launch_bounds__(256, 4) void pq_kernel(
    const float* __restrict__ h, const u16* __restrict__ wt,
    const float* __restrict__ be1,
    u16* __restrict__ Pt, u16* __restrict__ Qt, int N)
{
    __shared__ __align__(16) u16 sA[64 * SHS];
    __shared__ __align__(16) u16 sO[64 * SHS];

    const int t = threadIdx.x;
    const int lane = t & 63;
    const int wid = t >> 6;
    const int n0 = blockIdx.x * 64;

    // stage h (f32 -> bf16) [64][128]
    {
        const int e = t & 63, q = t >> 6;
        int ng = n0 + e; int ns = (ng < N) ? ng : N - 1;
        const float4* src = (const float4*)(h + (size_t)ns * D + q * 32);
        u16* dst = sA + e * SHS + q * 32;
        #pragma unroll
        for (int c = 0; c < 4; ++c) {
            float4 a = src[2 * c], b = src[2 * c + 1];
            u32 p0 = (u32)f2bf(a.x) | ((u32)f2bf(a.y) << 16);
            u32 p1 = (u32)f2bf(a.z) | ((u32)f2bf(a.w) << 16);
            u32 p2 = (u32)f2bf(b.x) | ((u32)f2bf(b.y) << 16);
            u32 p3 = (u32)f2bf(b.z) | ((u32)f2bf(b.w) << 16);
            *(uint4*)(dst + c * 8) = make_uint4(p0, p1, p2, p3);
        }
    }
    __syncthreads();

    const int lrow = lane & 15;
    const int kg = lane >> 4;
    const int g4 = kg * 4;
    const int nbase = wid * 32;

    f32x4 accP[4][2] = {}, accQ[4][2] = {};
    {
        bf16x8 Bt[8], Bm[8];
        #pragma unroll
        for (int nn = 0; nn < 2; ++nn)
            #pragma unroll
            for (int s = 0; s < 4; ++s) {
                const u16* bp = wt + (size_t)(nbase + nn * 16 + lrow) * 256 + s * 32 + kg * 8;
                Bt[nn * 4 + s] = *(const bf16x8*)bp;
                Bm[nn * 4 + s] = *(const bf16x8*)(bp + 128);
            }
        #pragma unroll
        for (int s = 0; s < 4; ++s) {
            bf16x8 a[4];
            #pragma unroll
            for (int m = 0; m < 4; ++m)
                a[m] = *(const bf16x8*)(sA + (m * 16 + lrow) * SHS + s * 32 + kg * 8);
            #pragma unroll
            for (int m = 0; m < 4; ++m)
                #pragma unroll
                for (int nn = 0; nn < 2; ++nn) {
                    accP[m][nn] = __builtin_amdgcn_mfma_f32_16x16x32_bf16(a[m], Bt[nn * 4 + s], accP[m][nn], 0, 0, 0);
                    accQ[m][nn] = __builtin_amdgcn_mfma_f32_16x16x32_bf16(a[m], Bm[nn * 4 + s], accQ[m][nn], 0, 0, 0);
                }
        }
    }

    // --- P: +be1, pack bf16, coalesced copy-out ---
    #pragma unroll
    for (int nn = 0; nn < 2; ++nn) {
        int outc = nbase + nn * 16 + lrow;
        float bb = be1[outc];
        #pragma unroll
        for (int m = 0; m < 4; ++m)
            #pragma unroll
            for (int r = 0; r < 4; ++r)
                sO[(m * 16 + g4 + r) * SHS + outc] = f2bf(accP[m][nn][r] + bb);
    }
    __syncthreads();
    {
        const int f4 = t & 15, rb = t >> 4;
        #pragma unroll
        for (int p = 0; p < 4; ++p) {
            int row = rb + p * 16;
            int ng = n0 + row;
            if (ng < N)
                *(uint4*)(Pt + (size_t)ng * D + f4 * 8) = *(const uint4*)(sO + row * SHS + f4 * 8);
        }
    }
    __syncthreads();
    // --- Q ---
    #pragma unroll
    for (int nn = 0; nn < 2; ++nn) {
        int outc = nbase + nn * 16 + lrow;
        #pragma unroll
        for (int m = 0; m < 4; ++m)
            #pragma unroll
            for (int r = 0; r < 4; ++r)
                sO[(m * 16 + g4 + r) * SHS + outc] = f2bf(accQ[m][nn][r]);
    }
    __syncthreads();
    {
        const int f4 = t & 15, rb = t >> 4;
        #pragma unroll
        for (int p = 0; p < 4; ++p) {
            int row = rb + p * 16;
            int ng = n0 + row;
            if (ng < N)
                *(uint4*)(Qt + (size_t)ng * D + f4 * 8) = *(const uint4*)(sO + row * SHS + f4 * 8);
        }
    }
}

// ---------------- edge model (P/Q path: no GEMM1; fused reduce) ----------------
__global__ __launch_bounds__(256, 4) void edge_pq_kernel(
    const u16* __restrict__ Pt, const u16* __restrict__ Qt,
    const int* __restrict__ ei, const int* __restrict__ perm,
    const float* __restrict__ coord, const float* __restrict__ lbox,
    const u16* __restrict__ wt, const float* __restrict__ We1,
    const float* __restrict__ be2,
    float* __restrict__ ef_out, float* __restrict__ aggf, int E)
{
    __shared__ __align__(16) u16 uni[64 * SFS * 2];   // 33792 B: sH1 (u16) / sXf (f32) union
    __shared__ int srow[64], scol[64], sEid[64];
    __shared__ float sRad[64];
    __shared__ float sW[128];
    u16* sH1 = uni;
    float* sXf = (float*)uni;

    const int t = threadIdx.x;
    const int lane = t & 63;
    const int wid = t >> 6;

    // bijective XCD swizzle (m204)
    int p0;
    {
        const int nwg = gridDim.x;
        const int orig = blockIdx.x;
        const int q = nwg >> 3, r = nwg & 7;
        const int xcd = orig & 7, idx = orig >> 3;
        const int tile = (xcd < r ? xcd * (q + 1) : r * (q + 1) + (xcd - r) * q) + idx;
        p0 = tile * 64;
    }

    if (t < 64) {
        int slot = p0 + t;
        int eg = perm[(slot < E) ? slot : (E - 1)];
        sEid[t] = (p0 + t < E) ? eg : -1;
        int rr = ei[eg];
        int cc = ei[(size_t)E + eg];
        srow[t] = rr;
        scol[t] = cc;
        float rad = 0.f;
        #pragma unroll
        for (int d3 = 0; d3 < 3; ++d3) {
            float df = coord[(size_t)rr * 3 + d3] - coord[(size_t)cc * 3 + d3];
            float ld = lbox[d3];
            df = (df >  0.5f * ld) ? df - ld : df;
            df = (df < -0.5f * ld) ? df + ld : df;
            rad += df * df;
        }
        sRad[t] = rad;
    } else if (t < 192) {
        sW[t - 64] = We1[(size_t)256 * D + (t - 64)];   // radial row of We1
    }
    __syncthreads();

    // phase 1: gather P[row]+Q[col], + rad*w, SiLU -> sH1 bf16
    {
        const int e = t & 63, q = t >> 6;
        const u16* Pp = Pt + (size_t)srow[e] * D;
        const u16* Qp = Qt + (size_t)scol[e] * D;
        const float rad = sRad[e];
        #pragma unroll
        for (int c0 = 0; c0 < 4; ++c0) {
            int j0 = q * 32 + c0 * 8;
            uint4 pu = *(const uint4*)(Pp + j0);
            uint4 qu = *(const uint4*)(Qp + j0);
            u32 pa[4] = {pu.x, pu.y, pu.z, pu.w};
            u32 qa[4] = {qu.x, qu.y, qu.z, qu.w};
            u32 ow[4];
            #pragma unroll
            for (int k = 0; k < 4; ++k) {
                float w0 = sW[j0 + 2 * k], w1 = sW[j0 + 2 * k + 1];
                float v0 = silu_f(bfl(pa[k]) + bfl(qa[k]) + rad * w0);
                float v1 = silu_f(bfh(pa[k]) + bfh(qa[k]) + rad * w1);
                ow[k] = (u32)f2bf(v0) | ((u32)f2bf(v1) << 16);
            }
            *(uint4*)(sH1 + e * SHS + j0) = make_uint4(ow[0], ow[1], ow[2], ow[3]);
        }
    }
    __syncthreads();

    const int lrow = lane & 15;
    const int kg = lane >> 4;
    const int g4 = kg * 4;
    const int nbase = wid * 32;

    // phase 2: GEMM2 (K=128)
    f32x4 acc2[4][2] = {};
    {
        bf16x8 B2[8];
        #pragma unroll
        for (int nn = 0; nn < 2; ++nn)
            #pragma unroll
            for (int s = 0; s < 4; ++s)
                B2[nn * 4 + s] = *(const bf16x8*)(wt + 32768 + (size_t)(nbase + nn * 16 + lrow) * 128 + s * 32 + kg * 8);
        #pragma unroll
        for (int s = 0; s < 4; ++s) {
            bf16x8 a[4];
            #pragma unroll
            for (int m = 0; m < 4; ++m)
                a[m] = *(const bf16x8*)(sH1 + (m * 16 + lrow) * SHS + s * 32 + kg * 8);
            #pragma unroll
            for (int m = 0; m < 4; ++m)
                #pragma unroll
                for (int nn = 0; nn < 2; ++nn)
                    acc2[m][nn] = __builtin_amdgcn_mfma_f32_16x16x32_bf16(a[m], B2[nn * 4 + s], acc2[m][nn], 0, 0, 0);
        }
    }
    __syncthreads();   // sH1 dead before sXf overwrite

    // phase 3: bias + SiLU -> f32 buffer
    #pragma unroll
    for (int nn = 0; nn < 2; ++nn) {
        int outc = nbase + nn * 16 + lrow;
        float bb = be2[outc];
        #pragma unroll
        for (int m = 0; m < 4; ++m)
            #pragma unroll
            for (int r = 0; r < 4; ++r)
                sXf[(m * 16 + g4 + r) * SFS + outc] = silu_f(acc2[m][nn][r] + bb);
    }
    __syncthreads();

    // phase 4: merged ef write (NT) + segmented reduce into aggf
    {
        const int ct = t & 127;
        const int half = t >> 7;
        const int ebeg = half * 32, eend = ebeg + 32;
        float run = 0.f;
        int prev = srow[ebeg];
        for (int e = ebeg; e < eend; ++e) {
            int r = srow[e];
            if (r != prev) {
                if (run != 0.f) atomicAdd(&aggf[(size_t)prev * D + ct], run);
                run = 0.f; prev = r;
            }
            int eg = sEid[e];
            if (eg >= 0) {
                float v = sXf[e * SFS + ct];
                __builtin_nontemporal_store(v, &ef_out[(size_t)eg * D + ct]);
                run += v;
            }
        }
        if (run != 0.f) atomicAdd(&aggf[(size_t)prev * D + ct], run);
    }
}

// ---------------- edge fallback (round-6 path, f32 staging, own GEMM1) ----------------
__global__ __launch_bounds__(256, 3) void edge_fb_kernel(
    const float* __restrict__ h,
    const int* __restrict__ ei, const int* __restrict__ perm,
    const float* __restrict__ coord, const float* __restrict__ lbox,
    const u16* __restrict__ wt,
    const float* __restrict__ We1, const float* __restrict__ be1,
    const float* __restrict__ be2,
    float* __restrict__ ef_out, float* __restrict__ aggf, int E)
{
    __shared__ __align__(16) u16 sX[64 * SXS];
    __shared__ __align__(16) u16 sH1[64 * SHS];
    __shared__ int srow[64], scol[64], sEid[64];
    __shared__ float sRad[64];

    const int t = threadIdx.x;
    const int lane = t & 63;
    const int wid = t >> 6;

    int p0;
    {
        const int nwg = gridDim.x;
        const int orig = blockIdx.x;
        const int q = nwg >> 3, r = nwg & 7;
        const int xcd = orig & 7, idx = orig >> 3;
        const int tile = (xcd < r ? xcd * (q + 1) : r * (q + 1) + (xcd - r) * q) + idx;
        p0 = tile * 64;
    }

    if (t < 64) {
        int slot = p0 + t;
        int eg = perm[(slot < E) ? slot : (E - 1)];
        sEid[t] = (p0 + t < E) ? eg : -1;
        srow[t] = ei[eg];
        scol[t] = ei[(size_t)E + eg];
    }
    __syncthreads();

    {
        const int e = t & 63;
        const int q = t >> 6;
        const int r = srow[e], c = scol[e];
        const float4* src = (const float4*)((q < 2) ? (h + (size_t)r * D + (q & 1) * 64)
                                                    : (h + (size_t)c * D + (q & 1) * 64));
        u16* dst = sX + e * SXS + q * 64;
        #pragma unroll
        for (int i = 0; i < 8; ++i) {
            float4 a = src[2 * i], b = src[2 * i + 1];
            u32 q0 = (u32)f2bf(a.x) | ((u32)f2bf(a.y) << 16);
            u32 q1 = (u32)f2bf(a.z) | ((u32)f2bf(a.w) << 16);
            u32 q2 = (u32)f2bf(b.x) | ((u32)f2bf(b.y) << 16);
            u32 q3 = (u32)f2bf(b.z) | ((u32)f2bf(b.w) << 16);
            *(uint4*)(dst + i * 8) = make_uint4(q0, q1, q2, q3);
        }
        if (t < 64) {
            int rr = srow[t], cc = scol[t];
            float rad = 0.f;
            #pragma unroll
            for (int d3 = 0; d3 < 3; ++d3) {
                float df = coord[(size_t)rr * 3 + d3] - coord[(size_t)cc * 3 + d3];
                float ld = lbox[d3];
                df = (df >  0.5f * ld) ? df - ld : df;
                df = (df < -0.5f * ld) ? df + ld : df;
                rad += df * df;
            }
            sRad[t] = rad;
        }
    }
    __syncthreads();

    const int lrow = lane & 15;
    const int kg = lane >> 4;
    const int g4 = kg * 4;
    const int nbase = wid * 32;

    f32x4 acc[4][2] = {};
    {
        bf16x8 B1[16];
        #pragma unroll
        for (int nn = 0; nn < 2; ++nn)
            #pragma unroll
            for (int s = 0; s < 8; ++s)
                B1[nn * 8 + s] = *(const bf16x8*)(wt + (size_t)(nbase + nn * 16 + lrow) * 256 + s * 32 + kg * 8);
        #pragma unroll
        for (int s = 0; s < 8; ++s) {
            bf16x8 a[4];
            #pragma unroll
            for (int m = 0; m < 4; ++m)
                a[m] = *(const bf16x8*)(sX + (m * 16 + lrow) * SXS + s * 32 + kg * 8);
            #pragma unroll
            for (int m = 0; m < 4; ++m)
                #pragma unroll
                for (int nn = 0; nn < 2; ++nn)
                    acc[m][nn] = __builtin_amdgcn_mfma_f32_16x16x32_bf16(a[m], B1[nn * 8 + s], acc[m][nn], 0, 0, 0);
        }
    }

    #pragma unroll
    for (int nn = 0; nn < 2; ++nn) {
        int outc = nbase + nn * 16 + lrow;
        float wl = We1[(size_t)256 * D + outc];
        float bb = be1[outc];
        #pragma unroll
        for (int m = 0; m < 4; ++m)
            #pragma unroll
            for (int r = 0; r < 4; ++r) {
                int e = m * 16 + g4 + r;
                float v = acc[m][nn][r] + sRad[e] * wl + bb;
                sH1[e * SHS + outc] = f2bf(silu_f(v));
            }
    }
    __syncthreads();

    f32x4 acc2[4][2] = {};
    {
        bf16x8 B2[8];
        #pragma unroll
        for (int nn = 0; nn < 2; ++nn)
            #pragma unroll
            for (int s = 0; s < 4; ++s)
                B2[nn * 4 + s] = *(const bf16x8*)(wt + 32768 + (size_t)(nbase + nn * 16 + lrow) * 128 + s * 32 + kg * 8);
        #pragma unroll
        for (int s = 0; s < 4; ++s) {
            bf16x8 a[4];
            #pragma unroll
            for (int m = 0; m < 4; ++m)
                a[m] = *(const bf16x8*)(sH1 + (m * 16 + lrow) * SHS + s * 32 + kg * 8);
            #pragma unroll
            for (int m = 0; m < 4; ++m)
                #pragma unroll
                for (int nn = 0; nn < 2; ++nn)
                    acc2[m][nn] = __builtin_amdgcn_mfma_f32_16x16x32_bf16(a[m], B2[nn * 4 + s], acc2[m][nn], 0, 0, 0);
        }
    }
    __syncthreads();

    float* sXf = (float*)sX;
    #pragma unroll
    for (int nn = 0; nn < 2; ++nn) {
        int outc = nbase + nn * 16 + lrow;
        float bb = be2[outc];
        #pragma unroll
        for (int m = 0; m < 4; ++m)
            #pragma unroll
            for (int r = 0; r < 4; ++r)
                sXf[(m * 16 + g4 + r) * SFS + outc] = silu_f(acc2[m][nn][r] + bb);
    }
    __syncthreads();

    {
        const int ct = t & 127;
        const int half = t >> 7;
        const int ebeg = half * 32, eend = ebeg + 32;
        float run = 0.f;
        int prev = srow[ebeg];
        for (int e = ebeg; e < eend; ++e) {
            int r = srow[e];
            if (r != prev) {
                if (run != 0.f) atomicAdd(&aggf[(size_t)prev * D + ct], run);
                run = 0.f; prev = r;
            }
            int eg = sEid[e];
            if (eg >= 0) {
                float v = sXf[e * SFS + ct];
                __builtin_nontemporal_store(v, &ef_out[(size_t)eg * D + ct]);
                run += v;
            }
        }
        if (run != 0.f) atomicAdd(&aggf[(size_t)prev * D + ct], run);
    }
}

// ---------------- node model (aliased LDS, f32 staging, 4 blocks/CU) ----------------
__global__ __launch_bounds__(256, 4) void node_kernel(
    const float* __restrict__ h, const float* __restrict__ aggf,
    const u16* __restrict__ wt,
    const float* __restrict__ bn1, const float* __restrict__ bn2,
    float* __restrict__ h_out, int N)
{
    __shared__ __align__(16) u16 uni[64 * SXS];   // 33792 B union: sX / sH1 / sXf
    u16* sX = uni;
    u16* sH1 = uni;
    float* sXf = (float*)uni;

    const int t = threadIdx.x;
    const int lane = t & 63;
    const int wid = t >> 6;
    const int n0 = blockIdx.x * 64;

    {
        const int e = t & 63;
        const int q = t >> 6;
        int ng = n0 + e; int ns = (ng < N) ? ng : N - 1;
        const float4* src = (const float4*)(((q < 2) ? h : aggf) + (size_t)ns * D + (q & 1) * 64);
        u16* dst = sX + e * SXS + q * 64;
        #pragma unroll
        for (int i = 0; i < 8; ++i) {
            float4 a = src[2 * i], b = src[2 * i + 1];
            u32 q0 = (u32)f2bf(a.x) | ((u32)f2bf(a.y) << 16);
            u32 q1 = (u32)f2bf(a.z) | ((u32)f2bf(a.w) << 16);
            u32 q2 = (u32)f2bf(b.x) | ((u32)f2bf(b.y) << 16);
            u32 q3 = (u32)f2bf(b.z) | ((u32)f2bf(b.w) << 16);
            *(uint4*)(dst + i * 8) = make_uint4(q0, q1, q2, q3);
        }
    }
    __syncthreads();

    const int lrow = lane & 15;
    const int kg = lane >> 4;
    const int g4 = kg * 4;
    const int nbase = wid * 32;

    f32x4 acc[4][2] = {};
    {
        bf16x8 B1[16];
        #pragma unroll
        for (int nn = 0; nn < 2; ++nn)
            #pragma unroll
            for (int s = 0; s < 8; ++s)
                B1[nn * 8 + s] = *(const bf16x8*)(wt + 49152 + (size_t)(nbase + nn * 16 + lrow) * 256 + s * 32 + kg * 8);
        #pragma unroll
        for (int s = 0; s < 8; ++s) {
            bf16x8 a[4];
            #pragma unroll
            for (int m = 0; m < 4; ++m)
                a[m] = *(const bf16x8*)(sX + (m * 16 + lrow) * SXS + s * 32 + kg * 8);
            #pragma unroll
            for (int m = 0; m < 4; ++m)
                #pragma unroll
                for (int nn = 0; nn < 2; ++nn)
                    acc[m][nn] = __builtin_amdgcn_mfma_f32_16x16x32_bf16(a[m], B1[nn * 8 + s], acc[m][nn], 0, 0, 0);
        }
    }
    __syncthreads();   // sX dead before sH1 overwrite

    #pragma unroll
    for (int nn = 0; nn < 2; ++nn) {
        int outc = nbase + nn * 16 + lrow;
        float bb = bn1[outc];
        #pragma unroll
        for (int m = 0; m < 4; ++m)
            #pragma unroll
            for (int r = 0; r < 4; ++r)
                sH1[(m * 16 + g4 + r) * SHS + outc] = f2bf(silu_f(acc[m][nn][r] + bb));
    }
    __syncthreads();

    f32x4 acc2[4][2] = {};
    {
        bf16x8 B2[8];
        #pragma unroll
        for (int nn = 0; nn < 2; ++nn)
            #pragma unroll
            for (int s = 0; s < 4; ++s)
                B2[nn * 4 + s] = *(const bf16x8*)(wt + 81920 + (size_t)(nbase + nn * 16 + lrow) * 128 + s * 32 + kg * 8);
        #pragma unroll
        for (int s = 0; s < 4; ++s) {
            bf16x8 a[4];
            #pragma unroll
            for (int m = 0; m < 4; ++m)
                a[m] = *(const bf16x8*)(sH1 + (m * 16 + lrow) * SHS + s * 32 + kg * 8);
            #pragma unroll
            for (int m = 0; m < 4; ++m)
                #pragma unroll
                for (int nn = 0; nn < 2; ++nn)
                    acc2[m][nn] = __builtin_amdgcn_mfma_f32_16x16x32_bf16(a[m], B2[nn * 4 + s], acc2[m][nn], 0, 0, 0);
        }
    }
    __syncthreads();   // sH1 dead before sXf overwrite

    #pragma unroll
    for (int nn = 0; nn < 2; ++nn) {
        int outc = nbase + nn * 16 + lrow;
        float bb = bn2[outc];
        #pragma unroll
        for (int m = 0; m < 4; ++m)
            #pragma unroll
            for (int r = 0; r < 4; ++r)
                sXf[(m * 16 + g4 + r) * SFS + outc] = acc2[m][nn][r] + bb;
    }
    __syncthreads();

    {
        const int f4 = t & 31;
        const int nb = t >> 5;
        #pragma unroll
        for (int i = 0; i < 8; ++i) {
            int nl = nb + i * 8;
            int ng = n0 + nl;
            if (ng < N) {
                f32x4 v = *(const f32x4*)&sXf[nl * SFS + f4 * 4];
                const f32x4 hv = *(const f32x4*)&h[(size_t)ng * D + f4 * 4];
                v += hv;
                __builtin_nontemporal_store(v, (f32x4*)&h_out[(size_t)ng * D + f4 * 4]);
            }
        }
    }
}

extern "C" void kernel_launch(void* const* d_in, const int* in_sizes, int n_in,
                              void* d_out, int out_size, void* d_ws, size_t ws_size,
                              hipStream_t stream) {
    const float* h     = (const float*)d_in[0];
    const int*   ei    = (const int*)d_in[1];
    const float* coord = (const float*)d_in[2];
    const float* lbox  = (const float*)d_in[4];
    const float* We1   = (const float*)d_in[5];
    const float* be1   = (const float*)d_in[6];
    const float* We2   = (const float*)d_in[7];
    const float* be2   = (const float*)d_in[8];
    const float* Wn1   = (const float*)d_in[9];
    const float* bn1   = (const float*)d_in[10];
    const float* Wn2   = (const float*)d_in[11];
    const float* bn2   = (const float*)d_in[12];

    const int N = in_sizes[0] / D;
    const int E = in_sizes[1] / 2;

    float* out       = (float*)d_out;
    float* h_out     = out;                       // [N,128]
    float* coord_out = out + (size_t)N * D;       // [N,3]
    float* ef_out    = coord_out + (size_t)N * 3; // [E,128]
    float* aggf      = h_out;                     // f32 agg accumulator in-place

    // workspace layout
    int* wsi = (int*)d_ws;
    u16* wt     = (u16*)d_ws;                     // 98304 u16 = 49152 ints
    int* offs   = wsi + 49152;                    // N+1 (padded N+8)
    int* cursor = offs + (N + 8);                 // N   (padded N+8)
    int* bsum   = cursor + (N + 8);               // 64
    int* perm   = bsum + 64;                      // E
    u16* Pt     = (u16*)(perm + E);               // N*128 bf16
    u16* Qt     = Pt + (size_t)N * D;             // N*128 bf16

    size_t need = (size_t)((char*)(Qt + (size_t)N * D) - (char*)d_ws);
    const bool use_pq = ws_size >= need;

    const int nb1 = (N + 1 + 1023) / 1024;        // scan1 blocks (<=64)

    prep_weights<<<384, 256, 0, stream>>>(We1, We2, Wn1, Wn2, wt);
    if (use_pq)
        pq_kernel<<<(N + 63) / 64, 256, 0, stream>>>(h, wt, be1, Pt, Qt, N);
    coord_kernel<<<(N * 3 + 255) / 256, 256, 0, stream>>>(coord, lbox, coord_out, N * 3);

    // zero agg accumulator (h_out region)
    hipMemsetAsync(aggf, 0, (size_t)N * D * sizeof(float), stream);

    // CSR build
    hipMemsetAsync(cursor, 0, (size_t)N * sizeof(int), stream);
    hist_kernel<<<(E + 255) / 256, 256, 0, stream>>>(ei, cursor, E);
    scan1_kernel<<<nb1, 256, 0, stream>>>(cursor, offs, bsum, N + 1);
    scan2_kernel<<<1, 64, 0, stream>>>(bsum, nb1);
    scan3_kernel<<<(N + 1 + 255) / 256, 256, 0, stream>>>(offs, bsum, cursor, N + 1);
    scatter_kernel<<<(E + 255) / 256, 256, 0, stream>>>(ei, cursor, perm, E);

    if (use_pq)
        edge_pq_kernel<<<(E + 63) / 64, 256, 0, stream>>>(
            Pt, Qt, ei, perm, coord, lbox, wt, We1, be2, ef_out, aggf, E);
    else
        edge_fb_kernel<<<(E + 63) / 64, 256, 0, stream>>>(
            h, ei, perm, coord, lbox, wt, We1, be1, be2, ef_out, aggf, E);

    node_kernel<<<(N + 63) / 64, 256, 0, stream>>>(
        h, aggf, wt, bn1, bn2, h_out, N);
}

// Round 8
// 274.712 us; speedup vs baseline: 5.5486x; 1.1302x over previous
//
#include <hip/hip_runtime.h>
#include <math.h>

#define D 128
#define SXS 264   // node sX stride (u16): 132 dwords
#define SHS 132   // layer-1 activation stride (u16): 66 dwords == 2 mod 8 -> conflict-free epi
#define SFS 132   // f32 out-buffer stride (dwords), fallback path

typedef unsigned int u32;
typedef unsigned short u16;
typedef __attribute__((ext_vector_type(8))) short bf16x8;
typedef __attribute__((ext_vector_type(4))) float f32x4;

__device__ __forceinline__ float bfl(u32 u) { return __uint_as_float(u << 16); }
__device__ __forceinline__ float bfh(u32 u) { return __uint_as_float(u & 0xFFFF0000u); }
__device__ __forceinline__ u16 f2bf(float f) {
    u32 u = __float_as_uint(f);
    return (u16)((u + 0x7FFFu + ((u >> 16) & 1u)) >> 16); // RNE (cold paths)
}
// HW packed f32->bf16 (RNE), 1 VALU op
__device__ __forceinline__ u32 cvt_pk_bf16(float lo, float hi) {
    u32 r;
    asm("v_cvt_pk_bf16_f32 %0, %1, %2" : "=v"(r) : "v"(lo), "v"(hi));
    return r;
}
__device__ __forceinline__ u16 cvt1_bf16(float v) { return (u16)cvt_pk_bf16(v, v); }
__device__ __forceinline__ float silu_f(float x) { return x / (1.0f + __expf(-x)); }

// ---------------- coord: out = remainder(coord, l) ----------------
__global__ void coord_kernel(const float* __restrict__ coord,
                             const float* __restrict__ lbox,
                             float* __restrict__ out, int n3) {
    int i = blockIdx.x * 256 + threadIdx.x;
    if (i < n3) {
        float ld = lbox[i % 3];
        float c = coord[i];
        float r = fmodf(c, ld);
        if (r < 0.f) r += ld;
        out[i] = r;
    }
}

// ---------------- weight prep: bf16 transposed Wt[n][k] into ws ----------------
__global__ void prep_weights(const float* __restrict__ We1, const float* __restrict__ We2,
                             const float* __restrict__ Wn1, const float* __restrict__ Wn2,
                             u16* __restrict__ wt) {
    int i = blockIdx.x * 256 + threadIdx.x;
    if (i < 32768)        { int n = i >> 8, k = i & 255;              wt[i] = f2bf(We1[(size_t)k*D + n]); }
    else if (i < 49152)   { int j = i - 32768; int n = j >> 7, k = j & 127; wt[i] = f2bf(We2[(size_t)k*D + n]); }
    else if (i < 81920)   { int j = i - 49152; int n = j >> 8, k = j & 255; wt[i] = f2bf(Wn1[(size_t)k*D + n]); }
    else if (i < 98304)   { int j = i - 81920; int n = j >> 7, k = j & 127; wt[i] = f2bf(Wn2[(size_t)k*D + n]); }
}

// ---------------- CSR build ----------------
__global__ void hist_kernel(const int* __restrict__ ei, int* __restrict__ cnt, int E) {
    int e = blockIdx.x * 256 + threadIdx.x;
    if (e < E) atomicAdd(&cnt[ei[e]], 1);
}

__global__ void scan1_kernel(const int* __restrict__ cnt, int* __restrict__ offs,
                             int* __restrict__ bsum, int n /* = N+1 */) {
    __shared__ int s[256];
    int t = threadIdx.x, b = blockIdx.x;
    int base = b * 1024 + t * 4;
    int v[4];
    #pragma unroll
    for (int i = 0; i < 4; ++i) { int idx = base + i; v[i] = (idx < n - 1) ? cnt[idx] : 0; }
    int lsum = v[0] + v[1] + v[2] + v[3];
    s[t] = lsum; __syncthreads();
    #pragma unroll
    for (int off = 1; off < 256; off <<= 1) {
        int x = (t >= off) ? s[t - off] : 0; __syncthreads();
        s[t] += x; __syncthreads();
    }
    int run = s[t] - lsum;
    #pragma unroll
    for (int i = 0; i < 4; ++i) { int idx = base + i; if (idx < n) offs[idx] = run; run += v[i]; }
    if (t == 255) bsum[b] = s[255];
}

__global__ void scan2_kernel(int* __restrict__ bsum, int nb) {
    __shared__ int s[64];
    int t = threadIdx.x;
    int orig = (t < nb) ? bsum[t] : 0;
    s[t] = orig; __syncthreads();
    #pragma unroll
    for (int off = 1; off < 64; off <<= 1) {
        int x = (t >= off) ? s[t - off] : 0; __syncthreads();
        s[t] += x; __syncthreads();
    }
    if (t < nb) bsum[t] = s[t] - orig;
}

__global__ void scan3_kernel(int* __restrict__ offs, const int* __restrict__ bsum,
                             int* __restrict__ cursor, int n) {
    int i = blockIdx.x * 256 + threadIdx.x;
    if (i < n) {
        int v = offs[i] + bsum[i >> 10];
        offs[i] = v;
        if (i < n - 1) cursor[i] = v;
    }
}

__global__ void scatter_kernel(const int* __restrict__ ei, int* __restrict__ cursor,
                               int* __restrict__ perm, int E) {
    int e = blockIdx.x * 256 + threadIdx.x;
    if (e < E) { int p = atomicAdd(&cursor[ei[e]], 1); perm[p] = e; }
}

// ---------------- P/Q precompute: P = h@W_top + be1, Q = h@W_mid (bf16) ----------------
__global__ __launch_bounds__(256, 4) void pq_kernel(
    const float* __restrict__ h, const u16* __restrict__ wt,
    const float* __restrict__ be1,
    u16* __restrict__ Pt, u16* __restrict__ Qt,
    int* __restrict__ cursor, int N)
{
    __shared__ __align__(16) u16 sA[64 * SHS];
    __shared__ __align__(16) u16 sO[64 * SHS];

    const int t = threadIdx.x;
    const int lane = t & 63;
    const int wid = t >> 6;
    const int n0 = blockIdx.x * 64;

    // zero the CSR count array (replaces a fill dispatch)
    if (t < 64) { int zi = n0 + t; if (zi < N) cursor[zi] = 0; }

    // stage h (f32 -> bf16) [64][128]
    {
        const int e = t & 63, q = t >> 6;
        int ng = n0 + e; int ns = (ng < N) ? ng : N - 1;
        const float4* src = (const float4*)(h + (size_t)ns * D + q * 32);
        u16* dst = sA + e * SHS + q * 32;
        #pragma unroll
        for (int c = 0; c < 4; ++c) {
            float4 a = src[2 * c], b = src[2 * c + 1];
            *(uint4*)(dst + c * 8) = make_uint4(cvt_pk_bf16(a.x, a.y), cvt_pk_bf16(a.z, a.w),
                                               cvt_pk_bf16(b.x, b.y), cvt_pk_bf16(b.z, b.w));
        }
    }
    __syncthreads();

    const int lrow = lane & 15;
    const int kg = lane >> 4;
    const int g4 = kg * 4;
    const int nbase = wid * 32;

    f32x4 accP[4][2] = {}, accQ[4][2] = {};
    {
        bf16x8 Bt[8], Bm[8];
        #pragma unroll
        for (int nn = 0; nn < 2; ++nn)
            #pragma unroll
            for (int s = 0; s < 4; ++s) {
                const u16* bp = wt + (size_t)(nbase + nn * 16 + lrow) * 256 + s * 32 + kg * 8;
                Bt[nn * 4 + s] = *(const bf16x8*)bp;
                Bm[nn * 4 + s] = *(const bf16x8*)(bp + 128);
            }
        #pragma unroll
        for (int s = 0; s < 4; ++s) {
            bf16x8 a[4];
            #pragma unroll
            for (int m = 0; m < 4; ++m)
                a[m] = *(const bf16x8*)(sA + (m * 16 + lrow) * SHS + s * 32 + kg * 8);
            #pragma unroll
            for (int m = 0; m < 4; ++m)
                #pragma unroll
                for (int nn = 0; nn < 2; ++nn) {
                    accP[m][nn] = __builtin_amdgcn_mfma_f32_16x16x32_bf16(a[m], Bt[nn * 4 + s], accP[m][nn], 0, 0, 0);
                    accQ[m][nn] = __builtin_amdgcn_mfma_f32_16x16x32_bf16(a[m], Bm[nn * 4 + s], accQ[m][nn], 0, 0, 0);
                }
        }
    }

    // --- P: +be1, pack bf16, coalesced copy-out ---
    #pragma unroll
    for (int nn = 0; nn < 2; ++nn) {
        int outc = nbase + nn * 16 + lrow;
        float bb = be1[outc];
        #pragma unroll
        for (int m = 0; m < 4; ++m)
            #pragma unroll
            for (int r = 0; r < 4; ++r)
                sO[(m * 16 + g4 + r) * SHS + outc] = cvt1_bf16(accP[m][nn][r] + bb);
    }
    __syncthreads();
    {
        const int f4 = t & 15, rb = t >> 4;
        #pragma unroll
        for (int p = 0; p < 4; ++p) {
            int row = rb + p * 16;
            int ng = n0 + row;
            if (ng < N)
                *(uint4*)(Pt + (size_t)ng * D + f4 * 8) = *(const uint4*)(sO + row * SHS + f4 * 8);
        }
    }
    __syncthreads();
    // --- Q ---
    #pragma unroll
    for (int nn = 0; nn < 2; ++nn) {
        int outc = nbase + nn * 16 + lrow;
        #pragma unroll
        for (int m = 0; m < 4; ++m)
            #pragma unroll
            for (int r = 0; r < 4; ++r)
                sO[(m * 16 + g4 + r) * SHS + outc] = cvt1_bf16(accQ[m][nn][r]);
    }
    __syncthreads();
    {
        const int f4 = t & 15, rb = t >> 4;
        #pragma unroll
        for (int p = 0; p < 4; ++p) {
            int row = rb + p * 16;
            int ng = n0 + row;
            if (ng < N)
                *(uint4*)(Qt + (size_t)ng * D + f4 * 8) = *(const uint4*)(sO + row * SHS + f4 * 8);
        }
    }
}

// ---------------- edge model (P/Q path; bf16 LDS union; 8 blocks/CU) ----------------
__global__ __launch_bounds__(256, 8) void edge_pq_kernel(
    const u16* __restrict__ Pt, const u16* __restrict__ Qt,
    const int* __restrict__ ei, const int* __restrict__ perm,
    const float* __restrict__ coord, const float* __restrict__ lbox,
    const u16* __restrict__ wt, const float* __restrict__ We1,
    const float* __restrict__ be2,
    float* __restrict__ ef_out, float* __restrict__ aggf, int E)
{
    __shared__ __align__(16) u16 uni[64 * SHS];   // 16896 B union: sH1 / sE16
    __shared__ int srow[64], scol[64], sEid[64];
    __shared__ float sRad[64];
    __shared__ float sW[128];
    u16* sH1 = uni;
    u16* sE16 = uni;

    const int t = threadIdx.x;
    const int lane = t & 63;
    const int wid = t >> 6;

    // bijective XCD swizzle (m204)
    int p0;
    {
        const int nwg = gridDim.x;
        const int orig = blockIdx.x;
        const int q = nwg >> 3, r = nwg & 7;
        const int xcd = orig & 7, idx = orig >> 3;
        const int tile = (xcd < r ? xcd * (q + 1) : r * (q + 1) + (xcd - r) * q) + idx;
        p0 = tile * 64;
    }

    if (t < 64) {
        int slot = p0 + t;
        int eg = perm[(slot < E) ? slot : (E - 1)];
        sEid[t] = (p0 + t < E) ? eg : -1;
        int rr = ei[eg];
        int cc = ei[(size_t)E + eg];
        srow[t] = rr;
        scol[t] = cc;
        float rad = 0.f;
        #pragma unroll
        for (int d3 = 0; d3 < 3; ++d3) {
            float df = coord[(size_t)rr * 3 + d3] - coord[(size_t)cc * 3 + d3];
            float ld = lbox[d3];
            df = (df >  0.5f * ld) ? df - ld : df;
            df = (df < -0.5f * ld) ? df + ld : df;
            rad += df * df;
        }
        sRad[t] = rad;
    } else if (t < 192) {
        sW[t - 64] = We1[(size_t)256 * D + (t - 64)];   // radial row of We1
    }
    __syncthreads();

    // phase 1: gather P[row]+Q[col], + rad*w, SiLU -> sH1 bf16
    {
        const int e = t & 63, q = t >> 6;
        const u16* Pp = Pt + (size_t)srow[e] * D;
        const u16* Qp = Qt + (size_t)scol[e] * D;
        const float rad = sRad[e];
        #pragma unroll
        for (int c0 = 0; c0 < 4; ++c0) {
            int j0 = q * 32 + c0 * 8;
            uint4 pu = *(const uint4*)(Pp + j0);
            uint4 qu = *(const uint4*)(Qp + j0);
            u32 pa[4] = {pu.x, pu.y, pu.z, pu.w};
            u32 qa[4] = {qu.x, qu.y, qu.z, qu.w};
            u32 ow[4];
            #pragma unroll
            for (int k = 0; k < 4; ++k) {
                float w0 = sW[j0 + 2 * k], w1 = sW[j0 + 2 * k + 1];
                float v0 = silu_f(bfl(pa[k]) + bfl(qa[k]) + rad * w0);
                float v1 = silu_f(bfh(pa[k]) + bfh(qa[k]) + rad * w1);
                ow[k] = cvt_pk_bf16(v0, v1);
            }
            *(uint4*)(sH1 + e * SHS + j0) = make_uint4(ow[0], ow[1], ow[2], ow[3]);
        }
    }
    __syncthreads();

    const int lrow = lane & 15;
    const int kg = lane >> 4;
    const int g4 = kg * 4;
    const int nbase = wid * 32;

    // phase 2: GEMM2 (K=128)
    f32x4 acc2[4][2] = {};
    {
        bf16x8 B2[8];
        #pragma unroll
        for (int nn = 0; nn < 2; ++nn)
            #pragma unroll
            for (int s = 0; s < 4; ++s)
                B2[nn * 4 + s] = *(const bf16x8*)(wt + 32768 + (size_t)(nbase + nn * 16 + lrow) * 128 + s * 32 + kg * 8);
        #pragma unroll
        for (int s = 0; s < 4; ++s) {
            bf16x8 a[4];
            #pragma unroll
            for (int m = 0; m < 4; ++m)
                a[m] = *(const bf16x8*)(sH1 + (m * 16 + lrow) * SHS + s * 32 + kg * 8);
            #pragma unroll
            for (int m = 0; m < 4; ++m)
                #pragma unroll
                for (int nn = 0; nn < 2; ++nn)
                    acc2[m][nn] = __builtin_amdgcn_mfma_f32_16x16x32_bf16(a[m], B2[nn * 4 + s], acc2[m][nn], 0, 0, 0);
        }
    }
    __syncthreads();   // sH1 dead before sE16 overwrite

    // phase 3: bias + SiLU -> bf16 buffer (same union)
    #pragma unroll
    for (int nn = 0; nn < 2; ++nn) {
        int outc = nbase + nn * 16 + lrow;
        float bb = be2[outc];
        #pragma unroll
        for (int m = 0; m < 4; ++m)
            #pragma unroll
            for (int r = 0; r < 4; ++r)
                sE16[(m * 16 + g4 + r) * SHS + outc] = cvt1_bf16(silu_f(acc2[m][nn][r] + bb));
    }
    __syncthreads();

    // phase 4: merged ef write (NT) + segmented reduce into aggf
    {
        const int ct = t & 127;
        const int half = t >> 7;
        const int ebeg = half * 32, eend = ebeg + 32;
        float run = 0.f;
        int prev = srow[ebeg];
        for (int e = ebeg; e < eend; ++e) {
            int r = srow[e];
            if (r != prev) {
                if (run != 0.f) atomicAdd(&aggf[(size_t)prev * D + ct], run);
                run = 0.f; prev = r;
            }
            int eg = sEid[e];
            if (eg >= 0) {
                float v = __uint_as_float((u32)sE16[e * SHS + ct] << 16);
                __builtin_nontemporal_store(v, &ef_out[(size_t)eg * D + ct]);
                run += v;
            }
        }
        if (run != 0.f) atomicAdd(&aggf[(size_t)prev * D + ct], run);
    }
}

// ---------------- edge fallback (f32 staging, own GEMM1) ----------------
__global__ __launch_bounds__(256, 3) void edge_fb_kernel(
    const float* __restrict__ h,
    const int* __restrict__ ei, const int* __restrict__ perm,
    const float* __restrict__ coord, const float* __restrict__ lbox,
    const u16* __restrict__ wt,
    const float* __restrict__ We1, const float* __restrict__ be1,
    const float* __restrict__ be2,
    float* __restrict__ ef_out, float* __restrict__ aggf, int E)
{
    __shared__ __align__(16) u16 sX[64 * SXS];
    __shared__ __align__(16) u16 sH1[64 * SHS];
    __shared__ int srow[64], scol[64], sEid[64];
    __shared__ float sRad[64];

    const int t = threadIdx.x;
    const int lane = t & 63;
    const int wid = t >> 6;

    int p0;
    {
        const int nwg = gridDim.x;
        const int orig = blockIdx.x;
        const int q = nwg >> 3, r = nwg & 7;
        const int xcd = orig & 7, idx = orig >> 3;
        const int tile = (xcd < r ? xcd * (q + 1) : r * (q + 1) + (xcd - r) * q) + idx;
        p0 = tile * 64;
    }

    if (t < 64) {
        int slot = p0 + t;
        int eg = perm[(slot < E) ? slot : (E - 1)];
        sEid[t] = (p0 + t < E) ? eg : -1;
        srow[t] = ei[eg];
        scol[t] = ei[(size_t)E + eg];
    }
    __syncthreads();

    {
        const int e = t & 63;
        const int q = t >> 6;
        const int r = srow[e], c = scol[e];
        const float4* src = (const float4*)((q < 2) ? (h + (size_t)r * D + (q & 1) * 64)
                                                    : (h + (size_t)c * D + (q & 1) * 64));
        u16* dst = sX + e * SXS + q * 64;
        #pragma unroll
        for (int i = 0; i < 8; ++i) {
            float4 a = src[2 * i], b = src[2 * i + 1];
            *(uint4*)(dst + i * 8) = make_uint4(cvt_pk_bf16(a.x, a.y), cvt_pk_bf16(a.z, a.w),
                                               cvt_pk_bf16(b.x, b.y), cvt_pk_bf16(b.z, b.w));
        }
        if (t < 64) {
            int rr = srow[t], cc = scol[t];
            float rad = 0.f;
            #pragma unroll
            for (int d3 = 0; d3 < 3; ++d3) {
                float df = coord[(size_t)rr * 3 + d3] - coord[(size_t)cc * 3 + d3];
                float ld = lbox[d3];
                df = (df >  0.5f * ld) ? df - ld : df;
                df = (df < -0.5f * ld) ? df + ld : df;
                rad += df * df;
            }
            sRad[t] = rad;
        }
    }
    __syncthreads();

    const int lrow = lane & 15;
    const int kg = lane >> 4;
    const int g4 = kg * 4;
    const int nbase = wid * 32;

    f32x4 acc[4][2] = {};
    {
        bf16x8 B1[16];
        #pragma unroll
        for (int nn = 0; nn < 2; ++nn)
            #pragma unroll
            for (int s = 0; s < 8; ++s)
                B1[nn * 8 + s] = *(const bf16x8*)(wt + (size_t)(nbase + nn * 16 + lrow) * 256 + s * 32 + kg * 8);
        #pragma unroll
        for (int s = 0; s < 8; ++s) {
            bf16x8 a[4];
            #pragma unroll
            for (int m = 0; m < 4; ++m)
                a[m] = *(const bf16x8*)(sX + (m * 16 + lrow) * SXS + s * 32 + kg * 8);
            #pragma unroll
            for (int m = 0; m < 4; ++m)
                #pragma unroll
                for (int nn = 0; nn < 2; ++nn)
                    acc[m][nn] = __builtin_amdgcn_mfma_f32_16x16x32_bf16(a[m], B1[nn * 8 + s], acc[m][nn], 0, 0, 0);
        }
    }

    #pragma unroll
    for (int nn = 0; nn < 2; ++nn) {
        int outc = nbase + nn * 16 + lrow;
        float wl = We1[(size_t)256 * D + outc];
        float bb = be1[outc];
        #pragma unroll
        for (int m = 0; m < 4; ++m)
            #pragma unroll
            for (int r = 0; r < 4; ++r) {
                int e = m * 16 + g4 + r;
                float v = acc[m][nn][r] + sRad[e] * wl + bb;
                sH1[e * SHS + outc] = cvt1_bf16(silu_f(v));
            }
    }
    __syncthreads();

    f32x4 acc2[4][2] = {};
    {
        bf16x8 B2[8];
        #pragma unroll
        for (int nn = 0; nn < 2; ++nn)
            #pragma unroll
            for (int s = 0; s < 4; ++s)
                B2[nn * 4 + s] = *(const bf16x8*)(wt + 32768 + (size_t)(nbase + nn * 16 + lrow) * 128 + s * 32 + kg * 8);
        #pragma unroll
        for (int s = 0; s < 4; ++s) {
            bf16x8 a[4];
            #pragma unroll
            for (int m = 0; m < 4; ++m)
                a[m] = *(const bf16x8*)(sH1 + (m * 16 + lrow) * SHS + s * 32 + kg * 8);
            #pragma unroll
            for (int m = 0; m < 4; ++m)
                #pragma unroll
                for (int nn = 0; nn < 2; ++nn)
                    acc2[m][nn] = __builtin_amdgcn_mfma_f32_16x16x32_bf16(a[m], B2[nn * 4 + s], acc2[m][nn], 0, 0, 0);
        }
    }
    __syncthreads();

    float* sXf = (float*)sX;
    #pragma unroll
    for (int nn = 0; nn < 2; ++nn) {
        int outc = nbase + nn * 16 + lrow;
        float bb = be2[outc];
        #pragma unroll
        for (int m = 0; m < 4; ++m)
            #pragma unroll
            for (int r = 0; r < 4; ++r)
                sXf[(m * 16 + g4 + r) * SFS + outc] = silu_f(acc2[m][nn][r] + bb);
    }
    __syncthreads();

    {
        const int ct = t & 127;
        const int half = t >> 7;
        const int ebeg = half * 32, eend = ebeg + 32;
        float run = 0.f;
        int prev = srow[ebeg];
        for (int e = ebeg; e < eend; ++e) {
            int r = srow[e];
            if (r != prev) {
                if (run != 0.f) atomicAdd(&aggf[(size_t)prev * D + ct], run);
                run = 0.f; prev = r;
            }
            int eg = sEid[e];
            if (eg >= 0) {
                float v = sXf[e * SFS + ct];
                __builtin_nontemporal_store(v, &ef_out[(size_t)eg * D + ct]);
                run += v;
            }
        }
        if (run != 0.f) atomicAdd(&aggf[(size_t)prev * D + ct], run);
    }
}

// ---------------- node model (aliased LDS, 4 blocks/CU) ----------------
__global__ __launch_bounds__(256, 4) void node_kernel(
    const float* __restrict__ h, const float* __restrict__ aggf,
    const u16* __restrict__ wt,
    const float* __restrict__ bn1, const float* __restrict__ bn2,
    float* __restrict__ h_out, int N)
{
    __shared__ __align__(16) u16 uni[64 * SXS];   // 33792 B union: sX / sH1 / sXf
    u16* sX = uni;
    u16* sH1 = uni;
    float* sXf = (float*)uni;

    const int t = threadIdx.x;
    const int lane = t & 63;
    const int wid = t >> 6;
    const int n0 = blockIdx.x * 64;

    {
        const int e = t & 63;
        const int q = t >> 6;
        int ng = n0 + e; int ns = (ng < N) ? ng : N - 1;
        const float4* src = (const float4*)(((q < 2) ? h : aggf) + (size_t)ns * D + (q & 1) * 64);
        u16* dst = sX + e * SXS + q * 64;
        #pragma unroll
        for (int i = 0; i < 8; ++i) {
            float4 a = src[2 * i], b = src[2 * i + 1];
            *(uint4*)(dst + i * 8) = make_uint4(cvt_pk_bf16(a.x, a.y), cvt_pk_bf16(a.z, a.w),
                                               cvt_pk_bf16(b.x, b.y), cvt_pk_bf16(b.z, b.w));
        }
    }
    __syncthreads();

    const int lrow = lane & 15;
    const int kg = lane >> 4;
    const int g4 = kg * 4;
    const int nbase = wid * 32;

    f32x4 acc[4][2] = {};
    {
        bf16x8 B1[16];
        #pragma unroll
        for (int nn = 0; nn < 2; ++nn)
            #pragma unroll
            for (int s = 0; s < 8; ++s)
                B1[nn * 8 + s] = *(const bf16x8*)(wt + 49152 + (size_t)(nbase + nn * 16 + lrow) * 256 + s * 32 + kg * 8);
        #pragma unroll
        for (int s = 0; s < 8; ++s) {
            bf16x8 a[4];
            #pragma unroll
            for (int m = 0; m < 4; ++m)
                a[m] = *(const bf16x8*)(sX + (m * 16 + lrow) * SXS + s * 32 + kg * 8);
            #pragma unroll
            for (int m = 0; m < 4; ++m)
                #pragma unroll
                for (int nn = 0; nn < 2; ++nn)
                    acc[m][nn] = __builtin_amdgcn_mfma_f32_16x16x32_bf16(a[m], B1[nn * 8 + s], acc[m][nn], 0, 0, 0);
        }
    }
    __syncthreads();   // sX dead before sH1 overwrite

    #pragma unroll
    for (int nn = 0; nn < 2; ++nn) {
        int outc = nbase + nn * 16 + lrow;
        float bb = bn1[outc];
        #pragma unroll
        for (int m = 0; m < 4; ++m)
            #pragma unroll
            for (int r = 0; r < 4; ++r)
                sH1[(m * 16 + g4 + r) * SHS + outc] = cvt1_bf16(silu_f(acc[m][nn][r] + bb));
    }
    __syncthreads();

    f32x4 acc2[4][2] = {};
    {
        bf16x8 B2[8];
        #pragma unroll
        for (int nn = 0; nn < 2; ++nn)
            #pragma unroll
            for (int s = 0; s < 4; ++s)
                B2[nn * 4 + s] = *(const bf16x8*)(wt + 81920 + (size_t)(nbase + nn * 16 + lrow) * 128 + s * 32 + kg * 8);
        #pragma unroll
        for (int s = 0; s < 4; ++s) {
            bf16x8 a[4];
            #pragma unroll
            for (int m = 0; m < 4; ++m)
                a[m] = *(const bf16x8*)(sH1 + (m * 16 + lrow) * SHS + s * 32 + kg * 8);
            #pragma unroll
            for (int m = 0; m < 4; ++m)
                #pragma unroll
                for (int nn = 0; nn < 2; ++nn)
                    acc2[m][nn] = __builtin_amdgcn_mfma_f32_16x16x32_bf16(a[m], B2[nn * 4 + s], acc2[m][nn], 0, 0, 0);
        }
    }
    __syncthreads();   // sH1 dead before sXf overwrite

    #pragma unroll
    for (int nn = 0; nn < 2; ++nn) {
        int outc = nbase + nn * 16 + lrow;
        float bb = bn2[outc];
        #pragma unroll
        for (int m = 0; m < 4; ++m)
            #pragma unroll
            for (int r = 0; r < 4; ++r)
                sXf[(m * 16 + g4 + r) * SFS + outc] = acc2[m][nn][r] + bb;
    }
    __syncthreads();

    {
        const int f4 = t & 31;
        const int nb = t >> 5;
        #pragma unroll
        for (int i = 0; i < 8; ++i) {
            int nl = nb + i * 8;
            int ng = n0 + nl;
            if (ng < N) {
                f32x4 v = *(const f32x4*)&sXf[nl * SFS + f4 * 4];
                const f32x4 hv = *(const f32x4*)&h[(size_t)ng * D + f4 * 4];
                v += hv;
                __builtin_nontemporal_store(v, (f32x4*)&h_out[(size_t)ng * D + f4 * 4]);
            }
        }
    }
}

extern "C" void kernel_launch(void* const* d_in, const int* in_sizes, int n_in,
                              void* d_out, int out_size, void* d_ws, size_t ws_size,
                              hipStream_t stream) {
    const float* h     = (const float*)d_in[0];
    const int*   ei    = (const int*)d_in[1];
    const float* coord = (const float*)d_in[2];
    const float* lbox  = (const float*)d_in[4];
    const float* We1   = (const float*)d_in[5];
    const float* be1   = (const float*)d_in[6];
    const float* We2   = (const float*)d_in[7];
    const float* be2   = (const float*)d_in[8];
    const float* Wn1   = (const float*)d_in[9];
    const float* bn1   = (const float*)d_in[10];
    const float* Wn2   = (const float*)d_in[11];
    const float* bn2   = (const float*)d_in[12];

    const int N = in_sizes[0] / D;
    const int E = in_sizes[1] / 2;

    float* out       = (float*)d_out;
    float* h_out     = out;                       // [N,128]
    float* coord_out = out + (size_t)N * D;       // [N,3]
    float* ef_out    = coord_out + (size_t)N * 3; // [E,128]
    float* aggf      = h_out;                     // f32 agg accumulator in-place

    // workspace layout
    int* wsi = (int*)d_ws;
    u16* wt     = (u16*)d_ws;                     // 98304 u16 = 49152 ints
    int* offs   = wsi + 49152;                    // N+1 (padded N+8)
    int* cursor = offs + (N + 8);                 // N   (padded N+8)
    int* bsum   = cursor + (N + 8);               // 64
    int* perm   = bsum + 64;                      // E
    u16* Pt     = (u16*)(perm + E);               // N*128 bf16
    u16* Qt     = Pt + (size_t)N * D;             // N*128 bf16

    size_t need = (size_t)((char*)(Qt + (size_t)N * D) - (char*)d_ws);
    const bool use_pq = ws_size >= need;

    const int nb1 = (N + 1 + 1023) / 1024;        // scan1 blocks (<=64)

    prep_weights<<<384, 256, 0, stream>>>(We1, We2, Wn1, Wn2, wt);
    if (use_pq)
        pq_kernel<<<(N + 63) / 64, 256, 0, stream>>>(h, wt, be1, Pt, Qt, cursor, N);
    else
        hipMemsetAsync(cursor, 0, (size_t)N * sizeof(int), stream);
    coord_kernel<<<(N * 3 + 255) / 256, 256, 0, stream>>>(coord, lbox, coord_out, N * 3);

    // zero agg accumulator (h_out region)
    hipMemsetAsync(aggf, 0, (size_t)N * D * sizeof(float), stream);

    // CSR build
    hist_kernel<<<(E + 255) / 256, 256, 0, stream>>>(ei, cursor, E);
    scan1_kernel<<<nb1, 256, 0, stream>>>(cursor, offs, bsum, N + 1);
    scan2_kernel<<<1, 64, 0, stream>>>(bsum, nb1);
    scan3_kernel<<<(N + 1 + 255) / 256, 256, 0, stream>>>(offs, bsum, cursor, N + 1);
    scatter_kernel<<<(E + 255) / 256, 256, 0, stream>>>(ei, cursor, perm, E);

    if (use_pq)
        edge_pq_kernel<<<(E + 63) / 64, 256, 0, stream>>>(
            Pt, Qt, ei, perm, coord, lbox, wt, We1, be2, ef_out, aggf, E);
    else
        edge_fb_kernel<<<(E + 63) / 64, 256, 0, stream>>>(
            h, ei, perm, coord, lbox, wt, We1, be1, be2, ef_out, aggf, E);

    node_kernel<<<(N + 63) / 64, 256, 0, stream>>>(
        h, aggf, wt, bn1, bn2, h_out, N);
}